// Round 1
// baseline (8806.834 us; speedup 1.0000x reference)
//
#include <hip/hip_runtime.h>

#define NN 100000
#define NE 1600000

// ---------------- degree / norm kernels ----------------

__global__ void k_deg(const int* __restrict__ src, const int* __restrict__ dst,
                      float* __restrict__ dout, float* __restrict__ din) {
    int i = blockIdx.x * blockDim.x + threadIdx.x;
    if (i < NE) {
        atomicAdd(&dout[src[i]], 1.0f);
        atomicAdd(&din[dst[i]], 1.0f);
    }
}

__global__ void k_norm(float* __restrict__ a, float* __restrict__ b) {
    int i = blockIdx.x * blockDim.x + threadIdx.x;
    if (i < NN) {
        float v = a[i]; a[i] = (v > 0.f) ? rsqrtf(v) : 0.f;
        float w = b[i]; b[i] = (w > 0.f) ? rsqrtf(w) : 0.f;
    }
}

// ---------------- x passthrough copy ----------------

__global__ void k_copy4(const float4* __restrict__ in, float4* __restrict__ out, int n4) {
    int i = blockIdx.x * blockDim.x + threadIdx.x;
    if (i < n4) out[i] = in[i];
}

// ---------------- scatter-add aggregation (128 features) ----------------
// thread t = edge e (t>>5) x float4-chunk c (t&31); fused src-norm scaling.

__global__ void k_scatter128(const float* __restrict__ h, const int* __restrict__ src,
                             const int* __restrict__ dst, const float* __restrict__ ns,
                             float* __restrict__ agg) {
    long long t = (long long)blockIdx.x * blockDim.x + threadIdx.x;
    if (t >= (long long)NE * 32) return;
    int c = (int)(t & 31);
    int e = (int)(t >> 5);
    int s = src[e], d = dst[e];
    float nsv = ns[s];
    float4 v = *(const float4*)(h + (long long)s * 128 + c * 4);
    float* base = agg + (long long)d * 128 + c * 4;
    atomicAdd(base + 0, v.x * nsv);
    atomicAdd(base + 1, v.y * nsv);
    atomicAdd(base + 2, v.z * nsv);
    atomicAdd(base + 3, v.w * nsv);
}

// ---------------- per-node GEMM: out = (agg*nd) @ W + b (+relu) ----------------
// one block per node, blockDim == FOUT; agg row staged in LDS (broadcast reads).

template<int FOUT, bool RELU>
__global__ void k_gemm(const float* __restrict__ agg, const float* __restrict__ nd,
                       const float* __restrict__ W, const float* __restrict__ bias,
                       float* __restrict__ out) {
    __shared__ float s[128];
    int node = blockIdx.x;
    float scale = nd[node];
    for (int k = threadIdx.x; k < 128; k += blockDim.x)
        s[k] = agg[(long long)node * 128 + k] * scale;
    __syncthreads();
    int j = threadIdx.x;
    float acc = bias[j];
    #pragma unroll 16
    for (int k = 0; k < 128; ++k)
        acc = fmaf(s[k], W[k * FOUT + j], acc);
    if (RELU) acc = fmaxf(acc, 0.f);
    out[(long long)node * FOUT + j] = acc;
}

// ---------------- launch ----------------

extern "C" void kernel_launch(void* const* d_in, const int* in_sizes, int n_in,
                              void* d_out, int out_size, void* d_ws, size_t ws_size,
                              hipStream_t stream) {
    const float* x   = (const float*)d_in[0];
    const int* esrc  = (const int*)d_in[1];
    const int* edst  = (const int*)d_in[2];
    const float* W0  = (const float*)d_in[3];
    const float* b0  = (const float*)d_in[4];
    const float* W1  = (const float*)d_in[5];
    const float* b1  = (const float*)d_in[6];
    const float* W2  = (const float*)d_in[7];
    const float* b2  = (const float*)d_in[8];
    float* out = (float*)d_out;

    // workspace layout: norm_src [NN] | norm_dst [NN] | agg [NN*128]
    float* ns  = (float*)d_ws;
    float* nd  = ns + NN;
    float* agg = nd + NN;

    float* h1 = out + (long long)NN * 128;   // output chunk 1
    float* h2 = h1 + (long long)NN * 128;    // output chunk 2
    float* h3 = h2 + (long long)NN * 128;    // output chunk 3 (N x 64)

    // degrees -> norms
    hipMemsetAsync(ns, 0, (size_t)2 * NN * sizeof(float), stream);
    k_deg<<<(NE + 255) / 256, 256, 0, stream>>>(esrc, edst, ns, nd);
    k_norm<<<(NN + 255) / 256, 256, 0, stream>>>(ns, nd);

    // output 0: x passthrough
    k_copy4<<<(NN * 32 + 255) / 256, 256, 0, stream>>>((const float4*)x, (float4*)out, NN * 32);

    const long long st = (long long)NE * 32;
    const int sblocks = (int)((st + 255) / 256);
    const size_t aggBytes = (size_t)NN * 128 * sizeof(float);

    // layer 1: x -> h1 (relu)
    hipMemsetAsync(agg, 0, aggBytes, stream);
    k_scatter128<<<sblocks, 256, 0, stream>>>(x, esrc, edst, ns, agg);
    k_gemm<128, true><<<NN, 128, 0, stream>>>(agg, nd, W0, b0, h1);

    // layer 2: h1 -> h2 (relu)
    hipMemsetAsync(agg, 0, aggBytes, stream);
    k_scatter128<<<sblocks, 256, 0, stream>>>(h1, esrc, edst, ns, agg);
    k_gemm<128, true><<<NN, 128, 0, stream>>>(agg, nd, W1, b1, h2);

    // layer 3: h2 -> h3 (no relu)
    hipMemsetAsync(agg, 0, aggBytes, stream);
    k_scatter128<<<sblocks, 256, 0, stream>>>(h2, esrc, edst, ns, agg);
    k_gemm<64, false><<<NN, 64, 0, stream>>>(agg, nd, W2, b2, h3);
}

// Round 3
// 934.129 us; speedup vs baseline: 9.4279x; 9.4279x over previous
//
#include <hip/hip_runtime.h>

#define NN 100000
#define NE 1600000
#define NB 391   // ceil(NN/256)

// ---------------- degree histograms ----------------

__global__ void k_deg(const int* __restrict__ src, const int* __restrict__ dst,
                      int* __restrict__ cnt_out, int* __restrict__ cnt_in) {
    int i = blockIdx.x * blockDim.x + threadIdx.x;
    if (i < NE) {
        atomicAdd(&cnt_out[src[i]], 1);
        atomicAdd(&cnt_in[dst[i]], 1);
    }
}

__global__ void k_norm(const int* __restrict__ cnt_out, const int* __restrict__ cnt_in,
                       float* __restrict__ ns, float* __restrict__ nd) {
    int i = blockIdx.x * blockDim.x + threadIdx.x;
    if (i < NN) {
        int a = cnt_out[i]; ns[i] = (a > 0) ? rsqrtf((float)a) : 0.f;
        int b = cnt_in[i];  nd[i] = (b > 0) ? rsqrtf((float)b) : 0.f;
    }
}

// ---------------- exclusive scan of cnt_in -> rowptr (3-kernel) ----------------

__global__ void k_blocksum(const int* __restrict__ cnt, int* __restrict__ bsum) {
    __shared__ int s[256];
    int t = threadIdx.x;
    int i = blockIdx.x * 256 + t;
    s[t] = (i < NN) ? cnt[i] : 0;
    __syncthreads();
    for (int off = 128; off > 0; off >>= 1) {
        if (t < off) s[t] += s[t + off];
        __syncthreads();
    }
    if (t == 0) bsum[blockIdx.x] = s[0];
}

__global__ void k_scanb(const int* __restrict__ bsum, int* __restrict__ bsumex,
                        int* __restrict__ rowptr) {
    __shared__ int s[512];
    int t = threadIdx.x;
    int v = (t < NB) ? bsum[t] : 0;
    s[t] = v;
    __syncthreads();
    for (int off = 1; off < 512; off <<= 1) {
        int add = (t >= off) ? s[t - off] : 0;
        __syncthreads();
        s[t] += add;
        __syncthreads();
    }
    if (t < NB) bsumex[t] = s[t] - v;   // exclusive
    if (t == 0) rowptr[NN] = NE;
}

__global__ void k_rowptr(const int* __restrict__ cnt, const int* __restrict__ bsumex,
                         int* __restrict__ rowptr) {
    __shared__ int s[256];
    int t = threadIdx.x;
    int i = blockIdx.x * 256 + t;
    int v = (i < NN) ? cnt[i] : 0;
    s[t] = v;
    __syncthreads();
    for (int off = 1; off < 256; off <<= 1) {
        int add = (t >= off) ? s[t - off] : 0;
        __syncthreads();
        s[t] += add;
        __syncthreads();
    }
    if (i < NN) rowptr[i] = bsumex[blockIdx.x] + s[t] - v;  // exclusive
}

// ---------------- CSR fill: (src, ns[src]) per incoming edge ----------------

__global__ void k_fillcsr(const int* __restrict__ src, const int* __restrict__ dst,
                          const float* __restrict__ ns, const int* __restrict__ rowptr,
                          int* __restrict__ cursor, int* __restrict__ csrc,
                          float* __restrict__ csw) {
    int i = blockIdx.x * blockDim.x + threadIdx.x;
    if (i >= NE) return;
    int d = dst[i];
    int pos = atomicAdd(&cursor[d], 1);
    int o = rowptr[d] + pos;
    int s = src[i];
    csrc[o] = s;
    csw[o] = ns[s];
}

// ---------------- x passthrough ----------------

__global__ void k_copy4(const float4* __restrict__ in, float4* __restrict__ out, int n4) {
    int i = blockIdx.x * blockDim.x + threadIdx.x;
    if (i < n4) out[i] = in[i];
}

// ---------------- fused layer: aggregate (gather) + nd-scale + GEMM + bias (+relu) ----
// one block (128 threads) per node; thread t owns input feature t.

template<int FOUT, bool RELU>
__global__ __launch_bounds__(128)
void k_layer(const float* __restrict__ h, const int* __restrict__ rowptr,
             const int* __restrict__ csrc, const float* __restrict__ csw,
             const float* __restrict__ nd, const float* __restrict__ W,
             const float* __restrict__ bias, float* __restrict__ out) {
    __shared__ float s_agg[128];
    int node = blockIdx.x;
    int tid = threadIdx.x;
    int beg = rowptr[node], end = rowptr[node + 1];
    float acc = 0.f;
    int e = beg;
    for (; e + 1 < end; e += 2) {   // 2-way unroll: two gathers in flight
        int s0 = csrc[e];     int s1 = csrc[e + 1];
        float w0 = csw[e];    float w1 = csw[e + 1];
        float v0 = h[(long long)s0 * 128 + tid];
        float v1 = h[(long long)s1 * 128 + tid];
        acc = fmaf(v0, w0, acc);
        acc = fmaf(v1, w1, acc);
    }
    if (e < end) {
        int s0 = csrc[e];
        acc = fmaf(h[(long long)s0 * 128 + tid], csw[e], acc);
    }
    s_agg[tid] = acc * nd[node];
    __syncthreads();
    if (FOUT == 128 || tid < FOUT) {
        float o = bias[tid];
        #pragma unroll
        for (int k = 0; k < 128; ++k)
            o = fmaf(s_agg[k], W[k * FOUT + tid], o);
        if (RELU) o = fmaxf(o, 0.f);
        out[(long long)node * FOUT + tid] = o;
    }
}

// ---------------- layer 3 split: P = h2 @ W2 first (128->64), then aggregate 64 ----

__global__ __launch_bounds__(64)
void k_pregemm(const float* __restrict__ h2, const float* __restrict__ W2,
               float* __restrict__ P) {
    __shared__ float s[128];
    int node = blockIdx.x;
    int tid = threadIdx.x;  // 64
    s[tid]      = h2[(long long)node * 128 + tid];
    s[tid + 64] = h2[(long long)node * 128 + tid + 64];
    __syncthreads();
    float o = 0.f;
    #pragma unroll
    for (int k = 0; k < 128; ++k)
        o = fmaf(s[k], W2[k * 64 + tid], o);
    P[(long long)node * 64 + tid] = o;
}

__global__ __launch_bounds__(64)
void k_agg64(const float* __restrict__ P, const int* __restrict__ rowptr,
             const int* __restrict__ csrc, const float* __restrict__ csw,
             const float* __restrict__ nd, const float* __restrict__ bias,
             float* __restrict__ out) {
    int node = blockIdx.x;
    int tid = threadIdx.x;  // 64
    int beg = rowptr[node], end = rowptr[node + 1];
    float acc = 0.f;
    int e = beg;
    for (; e + 1 < end; e += 2) {
        int s0 = csrc[e];   int s1 = csrc[e + 1];
        float w0 = csw[e];  float w1 = csw[e + 1];
        float v0 = P[(long long)s0 * 64 + tid];
        float v1 = P[(long long)s1 * 64 + tid];
        acc = fmaf(v0, w0, acc);
        acc = fmaf(v1, w1, acc);
    }
    if (e < end) acc = fmaf(P[(long long)csrc[e] * 64 + tid], csw[e], acc);
    out[(long long)node * 64 + tid] = acc * nd[node] + bias[tid];
}

// ---------------- launch ----------------

extern "C" void kernel_launch(void* const* d_in, const int* in_sizes, int n_in,
                              void* d_out, int out_size, void* d_ws, size_t ws_size,
                              hipStream_t stream) {
    const float* x  = (const float*)d_in[0];
    const int* esrc = (const int*)d_in[1];
    const int* edst = (const int*)d_in[2];
    const float* W0 = (const float*)d_in[3];
    const float* b0 = (const float*)d_in[4];
    const float* W1 = (const float*)d_in[5];
    const float* b1 = (const float*)d_in[6];
    const float* W2 = (const float*)d_in[7];
    const float* b2 = (const float*)d_in[8];
    float* out = (float*)d_out;

    // workspace layout (all 4B elems), ~41 MB total. (NOTE: no trailing
    // backslashes in these comments -- a '\' at end of a // comment is a
    // line continuation and swallows the next declaration.)
    float* ns     = (float*)d_ws;          // NN
    float* nd     = ns + NN;               // NN
    int* cnt_out  = (int*)(nd + NN);       // NN  (contiguous with next two,
    int* cnt_in   = cnt_out + NN;          // NN   zeroed by one memset)
    int* cursor   = cnt_in + NN;           // NN
    int* rowptr   = cursor + NN;           // NN+1
    int* bsum     = rowptr + NN + 1;       // 512
    int* bsumex   = bsum + 512;            // 512
    int* csrc     = bsumex + 512;          // NE
    float* csw    = (float*)(csrc + NE);   // NE
    float* P      = csw + NE;              // NN*64

    float* h1 = out + (long long)NN * 128;
    float* h2 = h1 + (long long)NN * 128;
    float* h3 = h2 + (long long)NN * 128;

    // 1. zero counters (cnt_out, cnt_in, cursor contiguous)
    (void)hipMemsetAsync(cnt_out, 0, (size_t)3 * NN * sizeof(int), stream);

    // 2. degrees -> norms
    k_deg<<<(NE + 255) / 256, 256, 0, stream>>>(esrc, edst, cnt_out, cnt_in);
    k_norm<<<(NN + 255) / 256, 256, 0, stream>>>(cnt_out, cnt_in, ns, nd);

    // 3. scan cnt_in -> rowptr
    k_blocksum<<<NB, 256, 0, stream>>>(cnt_in, bsum);
    k_scanb<<<1, 512, 0, stream>>>(bsum, bsumex, rowptr);
    k_rowptr<<<NB, 256, 0, stream>>>(cnt_in, bsumex, rowptr);

    // 4. fill CSR (src id + src norm weight)
    k_fillcsr<<<(NE + 255) / 256, 256, 0, stream>>>(esrc, edst, ns, rowptr, cursor, csrc, csw);

    // 5. output 0: x passthrough
    k_copy4<<<(NN * 32 + 255) / 256, 256, 0, stream>>>((const float4*)x, (float4*)out, NN * 32);

    // 6. layers 1,2 fused (agg + gemm + relu)
    k_layer<128, true><<<NN, 128, 0, stream>>>(x,  rowptr, csrc, csw, nd, W0, b0, h1);
    k_layer<128, true><<<NN, 128, 0, stream>>>(h1, rowptr, csrc, csw, nd, W1, b1, h2);

    // 7. layer 3: gemm first (128->64), then aggregate 64 feats
    k_pregemm<<<NN, 64, 0, stream>>>(h2, W2, P);
    k_agg64<<<NN, 64, 0, stream>>>(P, rowptr, csrc, csw, nd, b2, h3);
}

// Round 4
// 933.097 us; speedup vs baseline: 9.4383x; 1.0011x over previous
//
#include <hip/hip_runtime.h>

#define NN 100000
#define NE 1600000
#define NB 391   // ceil(NN/256)

// ---------------- degree histograms ----------------

__global__ void k_deg(const int* __restrict__ src, const int* __restrict__ dst,
                      int* __restrict__ cnt_out, int* __restrict__ cnt_in) {
    int i = blockIdx.x * blockDim.x + threadIdx.x;
    if (i < NE) {
        atomicAdd(&cnt_out[src[i]], 1);
        atomicAdd(&cnt_in[dst[i]], 1);
    }
}

__global__ void k_norm(const int* __restrict__ cnt_out, const int* __restrict__ cnt_in,
                       float* __restrict__ ns, float* __restrict__ nd) {
    int i = blockIdx.x * blockDim.x + threadIdx.x;
    if (i < NN) {
        int a = cnt_out[i]; ns[i] = (a > 0) ? rsqrtf((float)a) : 0.f;
        int b = cnt_in[i];  nd[i] = (b > 0) ? rsqrtf((float)b) : 0.f;
    }
}

// ---------------- exclusive scan of cnt_in -> rowptr (3-kernel) ----------------

__global__ void k_blocksum(const int* __restrict__ cnt, int* __restrict__ bsum) {
    __shared__ int s[256];
    int t = threadIdx.x;
    int i = blockIdx.x * 256 + t;
    s[t] = (i < NN) ? cnt[i] : 0;
    __syncthreads();
    for (int off = 128; off > 0; off >>= 1) {
        if (t < off) s[t] += s[t + off];
        __syncthreads();
    }
    if (t == 0) bsum[blockIdx.x] = s[0];
}

__global__ void k_scanb(const int* __restrict__ bsum, int* __restrict__ bsumex,
                        int* __restrict__ rowptr) {
    __shared__ int s[512];
    int t = threadIdx.x;
    int v = (t < NB) ? bsum[t] : 0;
    s[t] = v;
    __syncthreads();
    for (int off = 1; off < 512; off <<= 1) {
        int add = (t >= off) ? s[t - off] : 0;
        __syncthreads();
        s[t] += add;
        __syncthreads();
    }
    if (t < NB) bsumex[t] = s[t] - v;   // exclusive
    if (t == 0) rowptr[NN] = NE;
}

__global__ void k_rowptr(const int* __restrict__ cnt, const int* __restrict__ bsumex,
                         int* __restrict__ rowptr) {
    __shared__ int s[256];
    int t = threadIdx.x;
    int i = blockIdx.x * 256 + t;
    int v = (i < NN) ? cnt[i] : 0;
    s[t] = v;
    __syncthreads();
    for (int off = 1; off < 256; off <<= 1) {
        int add = (t >= off) ? s[t - off] : 0;
        __syncthreads();
        s[t] += add;
        __syncthreads();
    }
    if (i < NN) rowptr[i] = bsumex[blockIdx.x] + s[t] - v;  // exclusive
}

// ---------------- CSR fill: packed (src, ns[src]) per incoming edge ----------------

__global__ void k_fillcsr(const int* __restrict__ src, const int* __restrict__ dst,
                          const float* __restrict__ ns, const int* __restrict__ rowptr,
                          int* __restrict__ cursor, int2* __restrict__ csr) {
    int i = blockIdx.x * blockDim.x + threadIdx.x;
    if (i >= NE) return;
    int d = dst[i];
    int pos = atomicAdd(&cursor[d], 1);
    int o = rowptr[d] + pos;
    int s = src[i];
    int2 sw;
    sw.x = s;
    sw.y = __float_as_int(ns[s]);
    csr[o] = sw;   // single 8-B store: one cache line touched per edge
}

// ---------------- x passthrough ----------------

__global__ void k_copy4(const float4* __restrict__ in, float4* __restrict__ out, int n4) {
    int i = blockIdx.x * blockDim.x + threadIdx.x;
    if (i < n4) out[i] = in[i];
}

// ---------------- fused layer: aggregate (gather) + nd-scale + GEMM + bias (+relu) ----
// 128 threads = 4 groups x 32 lanes; group g handles edges beg+g, beg+g+4, ...
// each lane loads a float4 (32 lanes x 16B = full 512B row per group).

template<bool RELU>
__global__ __launch_bounds__(128)
void k_layer(const float* __restrict__ h, const int* __restrict__ rowptr,
             const int2* __restrict__ csr, const float* __restrict__ nd,
             const float* __restrict__ W, const float* __restrict__ bias,
             float* __restrict__ out) {
    __shared__ float s_part[4][128];
    __shared__ float s_agg[128];
    int node = blockIdx.x;
    int tid = threadIdx.x;
    int g = tid >> 5;
    int lane = tid & 31;
    int beg = rowptr[node], end = rowptr[node + 1];
    float ndv = nd[node];

    float4 acc = make_float4(0.f, 0.f, 0.f, 0.f);
    int e = beg + g;
    for (; e + 4 < end; e += 8) {          // 2 edges in flight per group
        int2 sw0 = csr[e];
        int2 sw1 = csr[e + 4];
        float4 v0 = *(const float4*)(h + (long long)sw0.x * 128 + lane * 4);
        float4 v1 = *(const float4*)(h + (long long)sw1.x * 128 + lane * 4);
        float w0 = __int_as_float(sw0.y);
        float w1 = __int_as_float(sw1.y);
        acc.x = fmaf(v0.x, w0, acc.x); acc.y = fmaf(v0.y, w0, acc.y);
        acc.z = fmaf(v0.z, w0, acc.z); acc.w = fmaf(v0.w, w0, acc.w);
        acc.x = fmaf(v1.x, w1, acc.x); acc.y = fmaf(v1.y, w1, acc.y);
        acc.z = fmaf(v1.z, w1, acc.z); acc.w = fmaf(v1.w, w1, acc.w);
    }
    if (e < end) {                          // <=1 tail edge per group
        int2 sw = csr[e];
        float4 v = *(const float4*)(h + (long long)sw.x * 128 + lane * 4);
        float w = __int_as_float(sw.y);
        acc.x = fmaf(v.x, w, acc.x); acc.y = fmaf(v.y, w, acc.y);
        acc.z = fmaf(v.z, w, acc.z); acc.w = fmaf(v.w, w, acc.w);
    }
    *(float4*)&s_part[g][lane * 4] = acc;
    __syncthreads();

    float a = s_part[0][tid] + s_part[1][tid] + s_part[2][tid] + s_part[3][tid];
    s_agg[tid] = a * ndv;
    __syncthreads();

    float o = bias[tid];
    #pragma unroll
    for (int k4 = 0; k4 < 32; ++k4) {
        float4 sv = *(const float4*)&s_agg[k4 * 4];
        o = fmaf(sv.x, W[(k4 * 4 + 0) * 128 + tid], o);
        o = fmaf(sv.y, W[(k4 * 4 + 1) * 128 + tid], o);
        o = fmaf(sv.z, W[(k4 * 4 + 2) * 128 + tid], o);
        o = fmaf(sv.w, W[(k4 * 4 + 3) * 128 + tid], o);
    }
    if (RELU) o = fmaxf(o, 0.f);
    out[(long long)node * 128 + tid] = o;
}

// ---------------- layer 3 split: P = h2 @ W2 first (128->64), then aggregate 64 ----

__global__ __launch_bounds__(64)
void k_pregemm(const float* __restrict__ h2, const float* __restrict__ W2,
               float* __restrict__ P) {
    __shared__ float s[128];
    int node = blockIdx.x;
    int tid = threadIdx.x;  // 64
    s[tid]      = h2[(long long)node * 128 + tid];
    s[tid + 64] = h2[(long long)node * 128 + tid + 64];
    __syncthreads();
    float o = 0.f;
    #pragma unroll
    for (int k4 = 0; k4 < 32; ++k4) {
        float4 sv = *(const float4*)&s[k4 * 4];
        o = fmaf(sv.x, W2[(k4 * 4 + 0) * 64 + tid], o);
        o = fmaf(sv.y, W2[(k4 * 4 + 1) * 64 + tid], o);
        o = fmaf(sv.z, W2[(k4 * 4 + 2) * 64 + tid], o);
        o = fmaf(sv.w, W2[(k4 * 4 + 3) * 64 + tid], o);
    }
    P[(long long)node * 64 + tid] = o;
}

// 64 threads = 4 groups x 16 lanes; 16 lanes x float4 = full 256B row per group.
__global__ __launch_bounds__(64)
void k_agg64(const float* __restrict__ P, const int* __restrict__ rowptr,
             const int2* __restrict__ csr, const float* __restrict__ nd,
             const float* __restrict__ bias, float* __restrict__ out) {
    __shared__ float s_part[4][64];
    int node = blockIdx.x;
    int tid = threadIdx.x;
    int g = tid >> 4;
    int lane = tid & 15;
    int beg = rowptr[node], end = rowptr[node + 1];
    float ndv = nd[node];

    float4 acc = make_float4(0.f, 0.f, 0.f, 0.f);
    int e = beg + g;
    for (; e + 4 < end; e += 8) {
        int2 sw0 = csr[e];
        int2 sw1 = csr[e + 4];
        float4 v0 = *(const float4*)(P + (long long)sw0.x * 64 + lane * 4);
        float4 v1 = *(const float4*)(P + (long long)sw1.x * 64 + lane * 4);
        float w0 = __int_as_float(sw0.y);
        float w1 = __int_as_float(sw1.y);
        acc.x = fmaf(v0.x, w0, acc.x); acc.y = fmaf(v0.y, w0, acc.y);
        acc.z = fmaf(v0.z, w0, acc.z); acc.w = fmaf(v0.w, w0, acc.w);
        acc.x = fmaf(v1.x, w1, acc.x); acc.y = fmaf(v1.y, w1, acc.y);
        acc.z = fmaf(v1.z, w1, acc.z); acc.w = fmaf(v1.w, w1, acc.w);
    }
    if (e < end) {
        int2 sw = csr[e];
        float4 v = *(const float4*)(P + (long long)sw.x * 64 + lane * 4);
        float w = __int_as_float(sw.y);
        acc.x = fmaf(v.x, w, acc.x); acc.y = fmaf(v.y, w, acc.y);
        acc.z = fmaf(v.z, w, acc.z); acc.w = fmaf(v.w, w, acc.w);
    }
    *(float4*)&s_part[g][lane * 4] = acc;
    __syncthreads();

    float a = s_part[0][tid] + s_part[1][tid] + s_part[2][tid] + s_part[3][tid];
    out[(long long)node * 64 + tid] = a * ndv + bias[tid];
}

// ---------------- launch ----------------

extern "C" void kernel_launch(void* const* d_in, const int* in_sizes, int n_in,
                              void* d_out, int out_size, void* d_ws, size_t ws_size,
                              hipStream_t stream) {
    const float* x  = (const float*)d_in[0];
    const int* esrc = (const int*)d_in[1];
    const int* edst = (const int*)d_in[2];
    const float* W0 = (const float*)d_in[3];
    const float* b0 = (const float*)d_in[4];
    const float* W1 = (const float*)d_in[5];
    const float* b1 = (const float*)d_in[6];
    const float* W2 = (const float*)d_in[7];
    const float* b2 = (const float*)d_in[8];
    float* out = (float*)d_out;

    // workspace layout (4B elems, ~41 MB). NOTE: no trailing backslashes in
    // these comments (line-continuation would swallow the next declaration).
    float* ns     = (float*)d_ws;          // NN
    float* nd     = ns + NN;               // NN
    int* cnt_out  = (int*)(nd + NN);       // NN  (contiguous with next two;
    int* cnt_in   = cnt_out + NN;          // NN   zeroed by one memset)
    int* cursor   = cnt_in + NN;           // NN
    int* rowptr   = cursor + NN;           // NN+1
    int* bsum     = rowptr + NN + 1;       // 512
    int* bsumex   = bsum + 512;            // 512
    int2* csr     = (int2*)(bsumex + 512); // NE int2 (8-B aligned: offset even)
    float* P      = (float*)(csr + NE);    // NN*64

    float* h1 = out + (long long)NN * 128;
    float* h2 = h1 + (long long)NN * 128;
    float* h3 = h2 + (long long)NN * 128;

    // 1. zero counters (cnt_out, cnt_in, cursor contiguous)
    (void)hipMemsetAsync(cnt_out, 0, (size_t)3 * NN * sizeof(int), stream);

    // 2. degrees -> norms
    k_deg<<<(NE + 255) / 256, 256, 0, stream>>>(esrc, edst, cnt_out, cnt_in);
    k_norm<<<(NN + 255) / 256, 256, 0, stream>>>(cnt_out, cnt_in, ns, nd);

    // 3. scan cnt_in -> rowptr
    k_blocksum<<<NB, 256, 0, stream>>>(cnt_in, bsum);
    k_scanb<<<1, 512, 0, stream>>>(bsum, bsumex, rowptr);
    k_rowptr<<<NB, 256, 0, stream>>>(cnt_in, bsumex, rowptr);

    // 4. fill CSR (packed src id + src norm weight)
    k_fillcsr<<<(NE + 255) / 256, 256, 0, stream>>>(esrc, edst, ns, rowptr, cursor, csr);

    // 5. output 0: x passthrough
    k_copy4<<<(NN * 32 + 255) / 256, 256, 0, stream>>>((const float4*)x, (float4*)out, NN * 32);

    // 6. layers 1,2 fused (agg + gemm + relu)
    k_layer<true><<<NN, 128, 0, stream>>>(x,  rowptr, csr, nd, W0, b0, h1);
    k_layer<true><<<NN, 128, 0, stream>>>(h1, rowptr, csr, nd, W1, b1, h2);

    // 7. layer 3: gemm first (128->64), then aggregate 64 feats
    k_pregemm<<<NN, 64, 0, stream>>>(h2, W2, P);
    k_agg64<<<NN, 64, 0, stream>>>(P, rowptr, csr, nd, b2, h3);
}

// Round 5
// 866.266 us; speedup vs baseline: 10.1664x; 1.0771x over previous
//
#include <hip/hip_runtime.h>

#define NN 100000
#define NE 1600000
#define NB 391   // ceil(NN/256)

typedef unsigned int uint;
typedef unsigned short ushort;

__device__ __forceinline__ ushort f2bf(float f) {      // RNE fp32 -> bf16
    uint u = __float_as_uint(f);
    return (ushort)((u + 0x7FFFu + ((u >> 16) & 1u)) >> 16);
}

// decode 8 bf16 from a uint4 and fma into acc[8] with weight w
__device__ __forceinline__ void bf8_fma(uint4 q, float w, float* acc) {
    acc[0] = fmaf(__uint_as_float(q.x << 16),          w, acc[0]);
    acc[1] = fmaf(__uint_as_float(q.x & 0xFFFF0000u),  w, acc[1]);
    acc[2] = fmaf(__uint_as_float(q.y << 16),          w, acc[2]);
    acc[3] = fmaf(__uint_as_float(q.y & 0xFFFF0000u),  w, acc[3]);
    acc[4] = fmaf(__uint_as_float(q.z << 16),          w, acc[4]);
    acc[5] = fmaf(__uint_as_float(q.z & 0xFFFF0000u),  w, acc[5]);
    acc[6] = fmaf(__uint_as_float(q.w << 16),          w, acc[6]);
    acc[7] = fmaf(__uint_as_float(q.w & 0xFFFF0000u),  w, acc[7]);
}

// ---------------- degree histograms ----------------

__global__ void k_deg(const int* __restrict__ src, const int* __restrict__ dst,
                      int* __restrict__ cnt_out, int* __restrict__ cnt_in) {
    int i = blockIdx.x * blockDim.x + threadIdx.x;
    if (i < NE) {
        atomicAdd(&cnt_out[src[i]], 1);
        atomicAdd(&cnt_in[dst[i]], 1);
    }
}

__global__ void k_norm(const int* __restrict__ cnt_out, const int* __restrict__ cnt_in,
                       float* __restrict__ ns, float* __restrict__ nd) {
    int i = blockIdx.x * blockDim.x + threadIdx.x;
    if (i < NN) {
        int a = cnt_out[i]; ns[i] = (a > 0) ? rsqrtf((float)a) : 0.f;
        int b = cnt_in[i];  nd[i] = (b > 0) ? rsqrtf((float)b) : 0.f;
    }
}

// ---------------- exclusive scan of cnt_in -> rowptr (3-kernel) ----------------

__global__ void k_blocksum(const int* __restrict__ cnt, int* __restrict__ bsum) {
    __shared__ int s[256];
    int t = threadIdx.x;
    int i = blockIdx.x * 256 + t;
    s[t] = (i < NN) ? cnt[i] : 0;
    __syncthreads();
    for (int off = 128; off > 0; off >>= 1) {
        if (t < off) s[t] += s[t + off];
        __syncthreads();
    }
    if (t == 0) bsum[blockIdx.x] = s[0];
}

__global__ void k_scanb(const int* __restrict__ bsum, int* __restrict__ bsumex,
                        int* __restrict__ rowptr) {
    __shared__ int s[512];
    int t = threadIdx.x;
    int v = (t < NB) ? bsum[t] : 0;
    s[t] = v;
    __syncthreads();
    for (int off = 1; off < 512; off <<= 1) {
        int add = (t >= off) ? s[t - off] : 0;
        __syncthreads();
        s[t] += add;
        __syncthreads();
    }
    if (t < NB) bsumex[t] = s[t] - v;   // exclusive
    if (t == 0) rowptr[NN] = NE;
}

__global__ void k_rowptr(const int* __restrict__ cnt, const int* __restrict__ bsumex,
                         int* __restrict__ rowptr) {
    __shared__ int s[256];
    int t = threadIdx.x;
    int i = blockIdx.x * 256 + t;
    int v = (i < NN) ? cnt[i] : 0;
    s[t] = v;
    __syncthreads();
    for (int off = 1; off < 256; off <<= 1) {
        int add = (t >= off) ? s[t - off] : 0;
        __syncthreads();
        s[t] += add;
        __syncthreads();
    }
    if (i < NN) rowptr[i] = bsumex[blockIdx.x] + s[t] - v;  // exclusive
}

// ---------------- CSR fill: packed (src, ns[src]) per incoming edge ----------------

__global__ void k_fillcsr(const int* __restrict__ src, const int* __restrict__ dst,
                          const float* __restrict__ ns, const int* __restrict__ rowptr,
                          int* __restrict__ cursor, int2* __restrict__ csr) {
    int i = blockIdx.x * blockDim.x + threadIdx.x;
    if (i >= NE) return;
    int d = dst[i];
    int pos = atomicAdd(&cursor[d], 1);
    int o = rowptr[d] + pos;
    int s = src[i];
    int2 sw;
    sw.x = s;
    sw.y = __float_as_int(ns[s]);
    csr[o] = sw;
}

// ---------------- x passthrough + bf16 conversion ----------------

__global__ void k_copy_cvt(const float4* __restrict__ x, float4* __restrict__ out,
                           ushort* __restrict__ xb, int n4) {
    int i = blockIdx.x * blockDim.x + threadIdx.x;
    if (i < n4) {
        float4 v = x[i];
        out[i] = v;
        ushort4 b;
        b.x = f2bf(v.x); b.y = f2bf(v.y); b.z = f2bf(v.z); b.w = f2bf(v.w);
        *(ushort4*)(xb + (size_t)i * 4) = b;
    }
}

// ---------------- fused layer (bf16 gather, 4 nodes per block) ----------------
// 512 threads = 4 nodes x (8 groups x 16 lanes). Each 16-lane group loads a full
// 256-B bf16 row (uint4/lane = 8 feats). The 4 node-slices run the GEMM phase in
// lockstep over the same W stream -> W L2 traffic amortized 4x.

template<bool RELU, bool WB16>
__global__ __launch_bounds__(512)
void k_layer4(const ushort* __restrict__ hb, const int* __restrict__ rowptr,
              const int2* __restrict__ csr, const float* __restrict__ nd,
              const float* __restrict__ W, const float* __restrict__ bias,
              float* __restrict__ out, ushort* __restrict__ outb) {
    __shared__ float s_part[4][8][128];
    __shared__ float s_agg[4][128];
    int tid = threadIdx.x;
    int n = tid >> 7;           // local node 0..3
    int t = tid & 127;
    int g = t >> 4;             // group 0..7
    int lane = t & 15;
    int node = blockIdx.x * 4 + n;
    int beg = rowptr[node], end = rowptr[node + 1];

    float acc[8] = {0.f, 0.f, 0.f, 0.f, 0.f, 0.f, 0.f, 0.f};
    int e = beg + g;
    for (; e + 8 < end; e += 16) {          // 2 edges in flight per group
        int2 sw0 = csr[e];
        int2 sw1 = csr[e + 8];
        uint4 q0 = *(const uint4*)(hb + (size_t)sw0.x * 128 + lane * 8);
        uint4 q1 = *(const uint4*)(hb + (size_t)sw1.x * 128 + lane * 8);
        bf8_fma(q0, __int_as_float(sw0.y), acc);
        bf8_fma(q1, __int_as_float(sw1.y), acc);
    }
    if (e < end) {
        int2 sw = csr[e];
        uint4 q = *(const uint4*)(hb + (size_t)sw.x * 128 + lane * 8);
        bf8_fma(q, __int_as_float(sw.y), acc);
    }
    *(float4*)&s_part[n][g][lane * 8]     = make_float4(acc[0], acc[1], acc[2], acc[3]);
    *(float4*)&s_part[n][g][lane * 8 + 4] = make_float4(acc[4], acc[5], acc[6], acc[7]);
    __syncthreads();

    float a = 0.f;
    #pragma unroll
    for (int gg = 0; gg < 8; ++gg) a += s_part[n][gg][t];
    s_agg[n][t] = a * nd[node];
    __syncthreads();

    float o = bias[t];
    #pragma unroll
    for (int k4 = 0; k4 < 32; ++k4) {
        float4 sv = *(const float4*)&s_agg[n][k4 * 4];
        o = fmaf(sv.x, W[(k4 * 4 + 0) * 128 + t], o);
        o = fmaf(sv.y, W[(k4 * 4 + 1) * 128 + t], o);
        o = fmaf(sv.z, W[(k4 * 4 + 2) * 128 + t], o);
        o = fmaf(sv.w, W[(k4 * 4 + 3) * 128 + t], o);
    }
    if (RELU) o = fmaxf(o, 0.f);
    out[(size_t)node * 128 + t] = o;
    if (WB16) outb[(size_t)node * 128 + t] = f2bf(o);
}

// ---------------- layer 3 split: Pb = bf16(h2 @ W2), then aggregate 64 ----------

__global__ __launch_bounds__(256)
void k_pregemm4(const float* __restrict__ h2, const float* __restrict__ W2,
                ushort* __restrict__ Pb) {
    __shared__ float s[4][128];
    int tid = threadIdx.x;
    int n = tid >> 6;           // local node 0..3
    int t = tid & 63;
    int node = blockIdx.x * 4 + n;
    s[n][t]      = h2[(size_t)node * 128 + t];
    s[n][t + 64] = h2[(size_t)node * 128 + t + 64];
    __syncthreads();
    float o = 0.f;
    #pragma unroll
    for (int k4 = 0; k4 < 32; ++k4) {
        float4 sv = *(const float4*)&s[n][k4 * 4];
        o = fmaf(sv.x, W2[(k4 * 4 + 0) * 64 + t], o);
        o = fmaf(sv.y, W2[(k4 * 4 + 1) * 64 + t], o);
        o = fmaf(sv.z, W2[(k4 * 4 + 2) * 64 + t], o);
        o = fmaf(sv.w, W2[(k4 * 4 + 3) * 64 + t], o);
    }
    Pb[(size_t)node * 64 + t] = f2bf(o);
}

// 64 threads = 8 groups x 8 lanes; 8 lanes x 16B = full 128-B bf16 row per group.
__global__ __launch_bounds__(64)
void k_agg64b(const ushort* __restrict__ Pb, const int* __restrict__ rowptr,
              const int2* __restrict__ csr, const float* __restrict__ nd,
              const float* __restrict__ bias, float* __restrict__ out) {
    __shared__ float s_part[8][64];
    int tid = threadIdx.x;
    int g = tid >> 3;
    int lane = tid & 7;
    int node = blockIdx.x;
    int beg = rowptr[node], end = rowptr[node + 1];

    float acc[8] = {0.f, 0.f, 0.f, 0.f, 0.f, 0.f, 0.f, 0.f};
    int e = beg + g;
    for (; e + 8 < end; e += 16) {
        int2 sw0 = csr[e];
        int2 sw1 = csr[e + 8];
        uint4 q0 = *(const uint4*)(Pb + (size_t)sw0.x * 64 + lane * 8);
        uint4 q1 = *(const uint4*)(Pb + (size_t)sw1.x * 64 + lane * 8);
        bf8_fma(q0, __int_as_float(sw0.y), acc);
        bf8_fma(q1, __int_as_float(sw1.y), acc);
    }
    if (e < end) {
        int2 sw = csr[e];
        uint4 q = *(const uint4*)(Pb + (size_t)sw.x * 64 + lane * 8);
        bf8_fma(q, __int_as_float(sw.y), acc);
    }
    *(float4*)&s_part[g][lane * 8]     = make_float4(acc[0], acc[1], acc[2], acc[3]);
    *(float4*)&s_part[g][lane * 8 + 4] = make_float4(acc[4], acc[5], acc[6], acc[7]);
    __syncthreads();

    float a = 0.f;
    #pragma unroll
    for (int gg = 0; gg < 8; ++gg) a += s_part[gg][tid];
    out[(size_t)node * 64 + tid] = a * nd[node] + bias[tid];
}

// ---------------- launch ----------------

extern "C" void kernel_launch(void* const* d_in, const int* in_sizes, int n_in,
                              void* d_out, int out_size, void* d_ws, size_t ws_size,
                              hipStream_t stream) {
    const float* x  = (const float*)d_in[0];
    const int* esrc = (const int*)d_in[1];
    const int* edst = (const int*)d_in[2];
    const float* W0 = (const float*)d_in[3];
    const float* b0 = (const float*)d_in[4];
    const float* W1 = (const float*)d_in[5];
    const float* b1 = (const float*)d_in[6];
    const float* W2 = (const float*)d_in[7];
    const float* b2 = (const float*)d_in[8];
    float* out = (float*)d_out;

    // workspace (4-B units; ~28 MB). No trailing backslashes in comments.
    float* ns     = (float*)d_ws;               // NN
    float* nd     = ns + NN;                    // NN
    int* cnt_out  = (int*)(nd + NN);            // NN  (contiguous with next two;
    int* cnt_in   = cnt_out + NN;               // NN   zeroed by one memset)
    int* cursor   = cnt_in + NN;                // NN
    int* rowptr   = cursor + NN;                // NN+1 (padded to NN+8)
    int* bsum     = rowptr + NN + 8;            // 512
    int* bsumex   = bsum + 512;                 // 512
    int2* csr     = (int2*)(bsumex + 512);      // NE int2 (element offset even -> 8-B aligned)
    ushort* Pb    = (ushort*)(csr + NE);        // NN*64 bf16 (16-B aligned)

    // output chunks
    float* h1 = out + (size_t)NN * 128;
    float* h2 = h1 + (size_t)NN * 128;
    float* h3 = h2 + (size_t)NN * 128;          // NN*64 floats

    // bf16 scratch parked in dead output regions:
    //  xb16 in the h2 slot (dead until layer-2 writes h2; last read in layer 1)
    //  h1b16 in the h3 slot (dead until k_agg64b writes h3; last read in layer 2)
    ushort* xb16  = (ushort*)h2;                // NN*128 bf16 = 25.6 MB
    ushort* h1b16 = (ushort*)h3;                // NN*128 bf16 = 25.6 MB (slot is exactly 25.6 MB)

    // 1. zero counters (cnt_out, cnt_in, cursor contiguous)
    (void)hipMemsetAsync(cnt_out, 0, (size_t)3 * NN * sizeof(int), stream);

    // 2. degrees -> norms
    k_deg<<<(NE + 255) / 256, 256, 0, stream>>>(esrc, edst, cnt_out, cnt_in);
    k_norm<<<(NN + 255) / 256, 256, 0, stream>>>(cnt_out, cnt_in, ns, nd);

    // 3. scan cnt_in -> rowptr
    k_blocksum<<<NB, 256, 0, stream>>>(cnt_in, bsum);
    k_scanb<<<1, 512, 0, stream>>>(bsum, bsumex, rowptr);
    k_rowptr<<<NB, 256, 0, stream>>>(cnt_in, bsumex, rowptr);

    // 4. fill CSR (packed src id + src norm weight)
    k_fillcsr<<<(NE + 255) / 256, 256, 0, stream>>>(esrc, edst, ns, rowptr, cursor, csr);

    // 5. output 0: x passthrough + bf16 copy into h2 slot
    k_copy_cvt<<<(NN * 32 + 255) / 256, 256, 0, stream>>>((const float4*)x, (float4*)out,
                                                          xb16, NN * 32);

    // 6. layer 1: xb16 -> h1 (fp32 out + bf16 copy into h3 slot), relu
    k_layer4<true, true><<<NN / 4, 512, 0, stream>>>(xb16, rowptr, csr, nd, W0, b0, h1, h1b16);

    // 7. layer 2: h1b16 -> h2 (fp32 only; overwrites dead xb16), relu
    k_layer4<true, false><<<NN / 4, 512, 0, stream>>>(h1b16, rowptr, csr, nd, W1, b1, h2, nullptr);

    // 8. layer 3: Pb = bf16(h2 @ W2), then aggregate 64 feats -> h3 (overwrites dead h1b16)
    k_pregemm4<<<NN / 4, 256, 0, stream>>>(h2, W2, Pb);
    k_agg64b<<<NN, 64, 0, stream>>>(Pb, rowptr, csr, nd, b2, h3);
}

// Round 6
// 512.871 us; speedup vs baseline: 17.1716x; 1.6891x over previous
//
#include <hip/hip_runtime.h>

#define NN 100000
#define NE 1600000
#define NB 391   // ceil(NN/256)

typedef unsigned int uint;
typedef unsigned short ushort;
typedef __attribute__((ext_vector_type(8))) short short8;   // 8 bf16 MFMA frag
typedef __attribute__((ext_vector_type(4))) float f32x4;    // MFMA acc

__device__ __forceinline__ ushort f2bf(float f) {      // RNE fp32 -> bf16
    uint u = __float_as_uint(f);
    return (ushort)((u + 0x7FFFu + ((u >> 16) & 1u)) >> 16);
}

// decode 8 bf16 from a uint4 and fma into acc[8] with weight w
__device__ __forceinline__ void bf8_fma(uint4 q, float w, float* acc) {
    acc[0] = fmaf(__uint_as_float(q.x << 16),          w, acc[0]);
    acc[1] = fmaf(__uint_as_float(q.x & 0xFFFF0000u),  w, acc[1]);
    acc[2] = fmaf(__uint_as_float(q.y << 16),          w, acc[2]);
    acc[3] = fmaf(__uint_as_float(q.y & 0xFFFF0000u),  w, acc[3]);
    acc[4] = fmaf(__uint_as_float(q.z << 16),          w, acc[4]);
    acc[5] = fmaf(__uint_as_float(q.z & 0xFFFF0000u),  w, acc[5]);
    acc[6] = fmaf(__uint_as_float(q.w << 16),          w, acc[6]);
    acc[7] = fmaf(__uint_as_float(q.w & 0xFFFF0000u),  w, acc[7]);
}

// ---------------- degree histograms / norms ----------------

__global__ void k_deg(const int* __restrict__ src, const int* __restrict__ dst,
                      int* __restrict__ cnt_out, int* __restrict__ cnt_in) {
    int i = blockIdx.x * blockDim.x + threadIdx.x;
    if (i < NE) {
        atomicAdd(&cnt_out[src[i]], 1);
        atomicAdd(&cnt_in[dst[i]], 1);
    }
}

__global__ void k_norm(const int* __restrict__ cnt_out, const int* __restrict__ cnt_in,
                       float* __restrict__ ns, float* __restrict__ nd) {
    int i = blockIdx.x * blockDim.x + threadIdx.x;
    if (i < NN) {
        int a = cnt_out[i]; ns[i] = (a > 0) ? rsqrtf((float)a) : 0.f;
        int b = cnt_in[i];  nd[i] = (b > 0) ? rsqrtf((float)b) : 0.f;
    }
}

// ---------------- exclusive scan of cnt_in -> rowptr ----------------

__global__ void k_blocksum(const int* __restrict__ cnt, int* __restrict__ bsum) {
    __shared__ int s[256];
    int t = threadIdx.x;
    int i = blockIdx.x * 256 + t;
    s[t] = (i < NN) ? cnt[i] : 0;
    __syncthreads();
    for (int off = 128; off > 0; off >>= 1) {
        if (t < off) s[t] += s[t + off];
        __syncthreads();
    }
    if (t == 0) bsum[blockIdx.x] = s[0];
}

__global__ void k_scanb(const int* __restrict__ bsum, int* __restrict__ bsumex,
                        int* __restrict__ rowptr) {
    __shared__ int s[512];
    int t = threadIdx.x;
    int v = (t < NB) ? bsum[t] : 0;
    s[t] = v;
    __syncthreads();
    for (int off = 1; off < 512; off <<= 1) {
        int add = (t >= off) ? s[t - off] : 0;
        __syncthreads();
        s[t] += add;
        __syncthreads();
    }
    if (t < NB) bsumex[t] = s[t] - v;
    if (t == 0) rowptr[NN] = NE;
}

__global__ void k_rowptr(const int* __restrict__ cnt, const int* __restrict__ bsumex,
                         int* __restrict__ rowptr) {
    __shared__ int s[256];
    int t = threadIdx.x;
    int i = blockIdx.x * 256 + t;
    int v = (i < NN) ? cnt[i] : 0;
    s[t] = v;
    __syncthreads();
    for (int off = 1; off < 256; off <<= 1) {
        int add = (t >= off) ? s[t - off] : 0;
        __syncthreads();
        s[t] += add;
        __syncthreads();
    }
    if (i < NN) rowptr[i] = bsumex[blockIdx.x] + s[t] - v;
}

// ---------------- CSR fill ----------------

__global__ void k_fillcsr(const int* __restrict__ src, const int* __restrict__ dst,
                          const float* __restrict__ ns, const int* __restrict__ rowptr,
                          int* __restrict__ cursor, int2* __restrict__ csr) {
    int i = blockIdx.x * blockDim.x + threadIdx.x;
    if (i >= NE) return;
    int d = dst[i];
    int pos = atomicAdd(&cursor[d], 1);
    int o = rowptr[d] + pos;
    int s = src[i];
    int2 sw;
    sw.x = s;
    sw.y = __float_as_int(ns[s]);
    csr[o] = sw;
}

// ---------------- x passthrough ----------------

__global__ void k_copy4(const float4* __restrict__ in, float4* __restrict__ out, int n4) {
    int i = blockIdx.x * blockDim.x + threadIdx.x;
    if (i < n4) out[i] = in[i];
}

// ---------------- W transpose -> bf16 (WT[n][k] = bf16(W[k][n])) ----------------

template<int N>
__global__ void k_wt(const float* __restrict__ W, ushort* __restrict__ WT) {
    int i = blockIdx.x * 256 + threadIdx.x;
    if (i < N * 128) {
        int n = i >> 7, k = i & 127;
        WT[i] = f2bf(W[k * N + n]);
    }
}

// ---------------- dense MFMA GEMM: Cb[M x N] = bf16(A[M x 128] @ W) ----------------
// 256 thr = 4 waves; wave w owns cols [w*16*NT, w*16*NT + 16*NT). B-frags (W^T)
// loaded ONCE per block into registers; grid-stride over 16-row groups.
// Frag layouts (guide §3, m89/m92-verified): A/B lane l holds 8 contiguous
// k-elems at k=(l>>4)*8; C lane l reg r -> row=(l>>4)*4+r, col=l&15.

template<int NT, int N>
__global__ __launch_bounds__(256)
void k_gemm_mfma(const float* __restrict__ A, const ushort* __restrict__ WT,
                 ushort* __restrict__ Cb) {
    int tid = threadIdx.x;
    int w = tid >> 6;
    int l = tid & 63;
    int li = l & 15;
    int kg = l >> 4;           // 0..3
    short8 bfrag[NT][4];
    #pragma unroll
    for (int n = 0; n < NT; ++n) {
        int col = w * 16 * NT + n * 16 + li;
        #pragma unroll
        for (int kt = 0; kt < 4; ++kt)
            bfrag[n][kt] = *(const short8*)(WT + (size_t)col * 128 + kt * 32 + kg * 8);
    }
    for (int mg = blockIdx.x; mg < NN / 16; mg += gridDim.x) {
        int row = mg * 16 + li;
        short8 afrag[4];
        #pragma unroll
        for (int kt = 0; kt < 4; ++kt) {
            const float* ap = A + (size_t)row * 128 + kt * 32 + kg * 8;
            float4 a0 = *(const float4*)ap;
            float4 a1 = *(const float4*)(ap + 4);
            short8 af;
            af[0] = (short)f2bf(a0.x); af[1] = (short)f2bf(a0.y);
            af[2] = (short)f2bf(a0.z); af[3] = (short)f2bf(a0.w);
            af[4] = (short)f2bf(a1.x); af[5] = (short)f2bf(a1.y);
            af[6] = (short)f2bf(a1.z); af[7] = (short)f2bf(a1.w);
            afrag[kt] = af;
        }
        #pragma unroll
        for (int n = 0; n < NT; ++n) {
            f32x4 acc = {0.f, 0.f, 0.f, 0.f};
            #pragma unroll
            for (int kt = 0; kt < 4; ++kt)
                acc = __builtin_amdgcn_mfma_f32_16x16x32_bf16(afrag[kt], bfrag[n][kt], acc, 0, 0, 0);
            int ccol = w * 16 * NT + n * 16 + li;
            int crow = mg * 16 + kg * 4;
            #pragma unroll
            for (int r = 0; r < 4; ++r)
                Cb[(size_t)(crow + r) * N + ccol] = f2bf(acc[r]);
        }
    }
}

// ---------------- aggregation (no GEMM): out = [relu](nd * A.Yb + bias) ----------
// 256 thr = 16 groups x 16 lanes; one node per group; lane owns 8 feats.

template<bool RELU>
__global__ __launch_bounds__(256)
void k_agg128(const ushort* __restrict__ Yb, const int* __restrict__ rowptr,
              const int2* __restrict__ csr, const float* __restrict__ nd,
              const float* __restrict__ bias, float* __restrict__ out) {
    int tid = threadIdx.x;
    int grp = tid >> 4;
    int lane = tid & 15;
    int node = blockIdx.x * 16 + grp;
    int beg = rowptr[node], end = rowptr[node + 1];
    float acc[8] = {0.f, 0.f, 0.f, 0.f, 0.f, 0.f, 0.f, 0.f};
    int e = beg;
    for (; e + 3 < end; e += 4) {              // 4 gathers in flight
        int2 s0 = csr[e];     int2 s1 = csr[e + 1];
        int2 s2 = csr[e + 2]; int2 s3 = csr[e + 3];
        uint4 q0 = *(const uint4*)(Yb + (size_t)s0.x * 128 + lane * 8);
        uint4 q1 = *(const uint4*)(Yb + (size_t)s1.x * 128 + lane * 8);
        uint4 q2 = *(const uint4*)(Yb + (size_t)s2.x * 128 + lane * 8);
        uint4 q3 = *(const uint4*)(Yb + (size_t)s3.x * 128 + lane * 8);
        bf8_fma(q0, __int_as_float(s0.y), acc);
        bf8_fma(q1, __int_as_float(s1.y), acc);
        bf8_fma(q2, __int_as_float(s2.y), acc);
        bf8_fma(q3, __int_as_float(s3.y), acc);
    }
    for (; e < end; ++e) {
        int2 s = csr[e];
        uint4 q = *(const uint4*)(Yb + (size_t)s.x * 128 + lane * 8);
        bf8_fma(q, __int_as_float(s.y), acc);
    }
    float ndv = nd[node];
    float4 b0 = *(const float4*)(bias + lane * 8);
    float4 b1 = *(const float4*)(bias + lane * 8 + 4);
    float4 o0, o1;
    o0.x = acc[0] * ndv + b0.x; o0.y = acc[1] * ndv + b0.y;
    o0.z = acc[2] * ndv + b0.z; o0.w = acc[3] * ndv + b0.w;
    o1.x = acc[4] * ndv + b1.x; o1.y = acc[5] * ndv + b1.y;
    o1.z = acc[6] * ndv + b1.z; o1.w = acc[7] * ndv + b1.w;
    if (RELU) {
        o0.x = fmaxf(o0.x, 0.f); o0.y = fmaxf(o0.y, 0.f);
        o0.z = fmaxf(o0.z, 0.f); o0.w = fmaxf(o0.w, 0.f);
        o1.x = fmaxf(o1.x, 0.f); o1.y = fmaxf(o1.y, 0.f);
        o1.z = fmaxf(o1.z, 0.f); o1.w = fmaxf(o1.w, 0.f);
    }
    *(float4*)(out + (size_t)node * 128 + lane * 8)     = o0;
    *(float4*)(out + (size_t)node * 128 + lane * 8 + 4) = o1;
}

// 256 thr = 32 groups x 8 lanes; one node per group; lane owns 8 of 64 feats.
__global__ __launch_bounds__(256)
void k_agg64(const ushort* __restrict__ Yb, const int* __restrict__ rowptr,
             const int2* __restrict__ csr, const float* __restrict__ nd,
             const float* __restrict__ bias, float* __restrict__ out) {
    int tid = threadIdx.x;
    int grp = tid >> 3;
    int lane = tid & 7;
    int node = blockIdx.x * 32 + grp;
    int beg = rowptr[node], end = rowptr[node + 1];
    float acc[8] = {0.f, 0.f, 0.f, 0.f, 0.f, 0.f, 0.f, 0.f};
    int e = beg;
    for (; e + 3 < end; e += 4) {
        int2 s0 = csr[e];     int2 s1 = csr[e + 1];
        int2 s2 = csr[e + 2]; int2 s3 = csr[e + 3];
        uint4 q0 = *(const uint4*)(Yb + (size_t)s0.x * 64 + lane * 8);
        uint4 q1 = *(const uint4*)(Yb + (size_t)s1.x * 64 + lane * 8);
        uint4 q2 = *(const uint4*)(Yb + (size_t)s2.x * 64 + lane * 8);
        uint4 q3 = *(const uint4*)(Yb + (size_t)s3.x * 64 + lane * 8);
        bf8_fma(q0, __int_as_float(s0.y), acc);
        bf8_fma(q1, __int_as_float(s1.y), acc);
        bf8_fma(q2, __int_as_float(s2.y), acc);
        bf8_fma(q3, __int_as_float(s3.y), acc);
    }
    for (; e < end; ++e) {
        int2 s = csr[e];
        uint4 q = *(const uint4*)(Yb + (size_t)s.x * 64 + lane * 8);
        bf8_fma(q, __int_as_float(s.y), acc);
    }
    float ndv = nd[node];
    float4 b0 = *(const float4*)(bias + lane * 8);
    float4 b1 = *(const float4*)(bias + lane * 8 + 4);
    float4 o0, o1;
    o0.x = acc[0] * ndv + b0.x; o0.y = acc[1] * ndv + b0.y;
    o0.z = acc[2] * ndv + b0.z; o0.w = acc[3] * ndv + b0.w;
    o1.x = acc[4] * ndv + b1.x; o1.y = acc[5] * ndv + b1.y;
    o1.z = acc[6] * ndv + b1.z; o1.w = acc[7] * ndv + b1.w;
    *(float4*)(out + (size_t)node * 64 + lane * 8)     = o0;
    *(float4*)(out + (size_t)node * 64 + lane * 8 + 4) = o1;
}

// ---------------- launch ----------------

extern "C" void kernel_launch(void* const* d_in, const int* in_sizes, int n_in,
                              void* d_out, int out_size, void* d_ws, size_t ws_size,
                              hipStream_t stream) {
    const float* x  = (const float*)d_in[0];
    const int* esrc = (const int*)d_in[1];
    const int* edst = (const int*)d_in[2];
    const float* W0 = (const float*)d_in[3];
    const float* b0 = (const float*)d_in[4];
    const float* W1 = (const float*)d_in[5];
    const float* b1 = (const float*)d_in[6];
    const float* W2 = (const float*)d_in[7];
    const float* b2 = (const float*)d_in[8];
    float* out = (float*)d_out;

    // workspace (4-B units; ~28 MB). No trailing backslashes in comments.
    float* ns     = (float*)d_ws;               // NN
    float* nd     = ns + NN;                    // NN
    int* cnt_out  = (int*)(nd + NN);            // NN  (contiguous with next two;
    int* cnt_in   = cnt_out + NN;               // NN   zeroed by one memset)
    int* cursor   = cnt_in + NN;                // NN
    int* rowptr   = cursor + NN;                // NN+1 (padded to NN+8)
    int* bsum     = rowptr + NN + 8;            // 512
    int* bsumex   = bsum + 512;                 // 512
    int2* csr     = (int2*)(bsumex + 512);      // NE int2 (offset even -> 8B aligned)
    ushort* WT0   = (ushort*)(csr + NE);        // 128*128 bf16 (16B aligned)
    ushort* WT1   = WT0 + 128 * 128;            // 128*128 bf16
    ushort* WT2   = WT1 + 128 * 128;            // 64*128 bf16
    ushort* Y2b   = WT2 + 64 * 128;             // NN*64 bf16 (offset stays 16B aligned)

    // output chunks
    float* h1 = out + (size_t)NN * 128;
    float* h2 = h1 + (size_t)NN * 128;
    float* h3 = h2 + (size_t)NN * 128;          // NN*64 floats

    // bf16 GEMM outputs parked in dead output slots:
    //  Y0b (x@W0)  in h2 slot: last read by agg layer-1; h2 written layer-2.
    //  Y1b (h1@W1) in h3 slot: last read by agg layer-2; h3 written layer-3.
    ushort* Y0b = (ushort*)h2;                  // NN*128 bf16 = 25.6 MB
    ushort* Y1b = (ushort*)h3;                  // NN*128 bf16 (slot exactly 25.6 MB)

    // 1. zero counters
    (void)hipMemsetAsync(cnt_out, 0, (size_t)3 * NN * sizeof(int), stream);

    // 2. degrees -> norms
    k_deg<<<(NE + 255) / 256, 256, 0, stream>>>(esrc, edst, cnt_out, cnt_in);
    k_norm<<<(NN + 255) / 256, 256, 0, stream>>>(cnt_out, cnt_in, ns, nd);

    // 3. scan cnt_in -> rowptr
    k_blocksum<<<NB, 256, 0, stream>>>(cnt_in, bsum);
    k_scanb<<<1, 512, 0, stream>>>(bsum, bsumex, rowptr);
    k_rowptr<<<NB, 256, 0, stream>>>(cnt_in, bsumex, rowptr);

    // 4. fill CSR
    k_fillcsr<<<(NE + 255) / 256, 256, 0, stream>>>(esrc, edst, ns, rowptr, cursor, csr);

    // 5. output 0: x passthrough
    k_copy4<<<(NN * 32 + 255) / 256, 256, 0, stream>>>((const float4*)x, (float4*)out, NN * 32);

    // 6. weight transposes (bf16)
    k_wt<128><<<64, 256, 0, stream>>>(W0, WT0);
    k_wt<128><<<64, 256, 0, stream>>>(W1, WT1);
    k_wt<64><<<32, 256, 0, stream>>>(W2, WT2);

    // 7. layer 1: Y0 = x@W0 (MFMA) -> aggregate -> h1 = relu(nd*agg + b0)
    k_gemm_mfma<2, 128><<<1024, 256, 0, stream>>>(x, WT0, Y0b);
    k_agg128<true><<<NN / 16, 256, 0, stream>>>(Y0b, rowptr, csr, nd, b0, h1);

    // 8. layer 2: Y1 = h1@W1 -> aggregate -> h2 (overwrites dead Y0b)
    k_gemm_mfma<2, 128><<<1024, 256, 0, stream>>>(h1, WT1, Y1b);
    k_agg128<true><<<NN / 16, 256, 0, stream>>>(Y1b, rowptr, csr, nd, b1, h2);

    // 9. layer 3: Y2 = h2@W2 (128->64) -> aggregate -> h3 (overwrites dead Y1b)
    k_gemm_mfma<1, 64><<<1024, 256, 0, stream>>>(h2, WT2, Y2b);
    k_agg64<<<NN / 32, 256, 0, stream>>>(Y2b, rowptr, csr, nd, b2, h3);
}

// Round 7
// 502.490 us; speedup vs baseline: 17.5264x; 1.0207x over previous
//
#include <hip/hip_runtime.h>

#define NN 100000
#define NE 1600000
#define NB 391   // ceil(NN/256)

typedef unsigned int uint;
typedef unsigned short ushort;
typedef __attribute__((ext_vector_type(8))) short short8;   // 8 bf16 MFMA frag
typedef __attribute__((ext_vector_type(4))) float f32x4;    // MFMA acc

__device__ __forceinline__ ushort f2bf(float f) {      // RNE fp32 -> bf16
    uint u = __float_as_uint(f);
    return (ushort)((u + 0x7FFFu + ((u >> 16) & 1u)) >> 16);
}

// decode 8 bf16 from a uint4 and add into acc[8] (weights pre-folded into rows)
__device__ __forceinline__ void bf8_add(uint4 q, float* acc) {
    acc[0] += __uint_as_float(q.x << 16);
    acc[1] += __uint_as_float(q.x & 0xFFFF0000u);
    acc[2] += __uint_as_float(q.y << 16);
    acc[3] += __uint_as_float(q.y & 0xFFFF0000u);
    acc[4] += __uint_as_float(q.z << 16);
    acc[5] += __uint_as_float(q.z & 0xFFFF0000u);
    acc[6] += __uint_as_float(q.w << 16);
    acc[7] += __uint_as_float(q.w & 0xFFFF0000u);
}

// ---------------- degree histograms (4-way interleaved replicas) ----------------
// cnt4 layout: out-degree at [node*4 + rep], in-degree at [4*NN + node*4 + rep].
// Replicas share the counter's cache line (same dirty-line footprint) but cut
// same-address atomic serialization 4x.

__global__ void k_deg(const int* __restrict__ src, const int* __restrict__ dst,
                      int* __restrict__ cnt4) {
    int i = blockIdx.x * blockDim.x + threadIdx.x;
    if (i < NE) {
        int r = i & 3;
        atomicAdd(&cnt4[src[i] * 4 + r], 1);
        atomicAdd(&cnt4[4 * NN + dst[i] * 4 + r], 1);
    }
}

__global__ void k_norm(const int4* __restrict__ co4, const int4* __restrict__ ci4,
                       float* __restrict__ ns, float* __restrict__ nd,
                       int* __restrict__ csum) {
    int i = blockIdx.x * blockDim.x + threadIdx.x;
    if (i < NN) {
        int4 a = co4[i];
        int da = a.x + a.y + a.z + a.w;
        ns[i] = (da > 0) ? rsqrtf((float)da) : 0.f;
        int4 b = ci4[i];
        int db = b.x + b.y + b.z + b.w;
        nd[i] = (db > 0) ? rsqrtf((float)db) : 0.f;
        csum[i] = db;
    }
}

// ---------------- exclusive scan of csum -> rowptr (+ 4-way sub-rowptr) --------

__global__ void k_blocksum(const int* __restrict__ cnt, int* __restrict__ bsum) {
    __shared__ int s[256];
    int t = threadIdx.x;
    int i = blockIdx.x * 256 + t;
    s[t] = (i < NN) ? cnt[i] : 0;
    __syncthreads();
    for (int off = 128; off > 0; off >>= 1) {
        if (t < off) s[t] += s[t + off];
        __syncthreads();
    }
    if (t == 0) bsum[blockIdx.x] = s[0];
}

__global__ void k_scanb(const int* __restrict__ bsum, int* __restrict__ bsumex,
                        int* __restrict__ rowptr) {
    __shared__ int s[512];
    int t = threadIdx.x;
    int v = (t < NB) ? bsum[t] : 0;
    s[t] = v;
    __syncthreads();
    for (int off = 1; off < 512; off <<= 1) {
        int add = (t >= off) ? s[t - off] : 0;
        __syncthreads();
        s[t] += add;
        __syncthreads();
    }
    if (t < NB) bsumex[t] = s[t] - v;
    if (t == 0) rowptr[NN] = NE;
}

__global__ void k_rowptr(const int* __restrict__ cnt, const int4* __restrict__ ci4,
                         const int* __restrict__ bsumex, int* __restrict__ rowptr,
                         int4* __restrict__ rowptr4) {
    __shared__ int s[256];
    int t = threadIdx.x;
    int i = blockIdx.x * 256 + t;
    int v = (i < NN) ? cnt[i] : 0;
    s[t] = v;
    __syncthreads();
    for (int off = 1; off < 256; off <<= 1) {
        int add = (t >= off) ? s[t - off] : 0;
        __syncthreads();
        s[t] += add;
        __syncthreads();
    }
    if (i < NN) {
        int base = bsumex[blockIdx.x] + s[t] - v;   // exclusive
        rowptr[i] = base;
        int4 c = ci4[i];
        int4 rp;
        rp.x = base;
        rp.y = base + c.x;
        rp.z = rp.y + c.y;
        rp.w = rp.z + c.z;
        rowptr4[i] = rp;
    }
}

// ---------------- CSR fill: src index only, 4-way replica cursors ----------------

__global__ void k_fillcsr(const int* __restrict__ src, const int* __restrict__ dst,
                          const int* __restrict__ rowptr4, int* __restrict__ cursor4,
                          int* __restrict__ csrc) {
    int i = blockIdx.x * blockDim.x + threadIdx.x;
    if (i >= NE) return;
    int d = dst[i];
    int r = i & 3;
    int pos = atomicAdd(&cursor4[d * 4 + r], 1);
    csrc[rowptr4[d * 4 + r] + pos] = src[i];
}

// ---------------- W transpose -> bf16 (WT[n][k] = bf16(W[k][n])) ----------------

template<int N>
__global__ void k_wt(const float* __restrict__ W, ushort* __restrict__ WT) {
    int i = blockIdx.x * 256 + threadIdx.x;
    if (i < N * 128) {
        int n = i >> 7, k = i & 127;
        WT[i] = f2bf(W[k * N + n]);
    }
}

// ---------------- dense MFMA GEMM: Cb[M x N] = bf16(ns_row * (A @ W)) ------------
// 256 thr = 4 waves; wave w owns cols [w*16*NT, ...). B-frags in registers,
// grid-stride over 16-row groups. ns folded into epilogue. Optional fp32
// passthrough copy of A (wave 0 only) for the layer-1 x output.
// Frag layouts (guide §3, m89/m92): A/B lane l: 8 contiguous k at k=(l>>4)*8;
// C lane l reg r: row=(l>>4)*4+r, col=l&15.

template<int NT, int N, bool COPY>
__global__ __launch_bounds__(256)
void k_gemm_mfma(const float* __restrict__ A, const ushort* __restrict__ WT,
                 const float* __restrict__ ns, ushort* __restrict__ Cb,
                 float* __restrict__ xout) {
    int tid = threadIdx.x;
    int w = tid >> 6;
    int l = tid & 63;
    int li = l & 15;
    int kg = l >> 4;           // 0..3
    short8 bfrag[NT][4];
    #pragma unroll
    for (int n = 0; n < NT; ++n) {
        int col = w * 16 * NT + n * 16 + li;
        #pragma unroll
        for (int kt = 0; kt < 4; ++kt)
            bfrag[n][kt] = *(const short8*)(WT + (size_t)col * 128 + kt * 32 + kg * 8);
    }
    for (int mg = blockIdx.x; mg < NN / 16; mg += gridDim.x) {
        int row = mg * 16 + li;
        short8 afrag[4];
        #pragma unroll
        for (int kt = 0; kt < 4; ++kt) {
            const float* ap = A + (size_t)row * 128 + kt * 32 + kg * 8;
            float4 a0 = *(const float4*)ap;
            float4 a1 = *(const float4*)(ap + 4);
            if (COPY && w == 0) {   // fused x-passthrough (each tile covered once)
                float* op = xout + (size_t)row * 128 + kt * 32 + kg * 8;
                *(float4*)op = a0;
                *(float4*)(op + 4) = a1;
            }
            short8 af;
            af[0] = (short)f2bf(a0.x); af[1] = (short)f2bf(a0.y);
            af[2] = (short)f2bf(a0.z); af[3] = (short)f2bf(a0.w);
            af[4] = (short)f2bf(a1.x); af[5] = (short)f2bf(a1.y);
            af[6] = (short)f2bf(a1.z); af[7] = (short)f2bf(a1.w);
            afrag[kt] = af;
        }
        int crow = mg * 16 + kg * 4;
        float4 nsv = *(const float4*)(ns + crow);     // crow % 4 == 0
        float nsa[4] = {nsv.x, nsv.y, nsv.z, nsv.w};
        #pragma unroll
        for (int n = 0; n < NT; ++n) {
            f32x4 acc = {0.f, 0.f, 0.f, 0.f};
            #pragma unroll
            for (int kt = 0; kt < 4; ++kt)
                acc = __builtin_amdgcn_mfma_f32_16x16x32_bf16(afrag[kt], bfrag[n][kt], acc, 0, 0, 0);
            int ccol = w * 16 * NT + n * 16 + li;
            #pragma unroll
            for (int r = 0; r < 4; ++r)
                Cb[(size_t)(crow + r) * N + ccol] = f2bf(acc[r] * nsa[r]);
        }
    }
}

// ---------------- aggregation: out = [relu](nd * sum_e Yb[src_e] + bias) ---------
// 256 thr = 16 groups x 16 lanes; one node per group; lane owns 8 feats.

template<bool RELU>
__global__ __launch_bounds__(256)
void k_agg128(const ushort* __restrict__ Yb, const int* __restrict__ rowptr,
              const int* __restrict__ csrc, const float* __restrict__ nd,
              const float* __restrict__ bias, float* __restrict__ out) {
    int tid = threadIdx.x;
    int grp = tid >> 4;
    int lane = tid & 15;
    int node = blockIdx.x * 16 + grp;
    int beg = rowptr[node], end = rowptr[node + 1];
    float acc[8] = {0.f, 0.f, 0.f, 0.f, 0.f, 0.f, 0.f, 0.f};
    int e = beg;
    for (; e + 3 < end; e += 4) {              // 4 gathers in flight
        int s0 = csrc[e];     int s1 = csrc[e + 1];
        int s2 = csrc[e + 2]; int s3 = csrc[e + 3];
        uint4 q0 = *(const uint4*)(Yb + (size_t)s0 * 128 + lane * 8);
        uint4 q1 = *(const uint4*)(Yb + (size_t)s1 * 128 + lane * 8);
        uint4 q2 = *(const uint4*)(Yb + (size_t)s2 * 128 + lane * 8);
        uint4 q3 = *(const uint4*)(Yb + (size_t)s3 * 128 + lane * 8);
        bf8_add(q0, acc); bf8_add(q1, acc); bf8_add(q2, acc); bf8_add(q3, acc);
    }
    for (; e < end; ++e) {
        uint4 q = *(const uint4*)(Yb + (size_t)csrc[e] * 128 + lane * 8);
        bf8_add(q, acc);
    }
    float ndv = nd[node];
    float4 b0 = *(const float4*)(bias + lane * 8);
    float4 b1 = *(const float4*)(bias + lane * 8 + 4);
    float4 o0, o1;
    o0.x = acc[0] * ndv + b0.x; o0.y = acc[1] * ndv + b0.y;
    o0.z = acc[2] * ndv + b0.z; o0.w = acc[3] * ndv + b0.w;
    o1.x = acc[4] * ndv + b1.x; o1.y = acc[5] * ndv + b1.y;
    o1.z = acc[6] * ndv + b1.z; o1.w = acc[7] * ndv + b1.w;
    if (RELU) {
        o0.x = fmaxf(o0.x, 0.f); o0.y = fmaxf(o0.y, 0.f);
        o0.z = fmaxf(o0.z, 0.f); o0.w = fmaxf(o0.w, 0.f);
        o1.x = fmaxf(o1.x, 0.f); o1.y = fmaxf(o1.y, 0.f);
        o1.z = fmaxf(o1.z, 0.f); o1.w = fmaxf(o1.w, 0.f);
    }
    *(float4*)(out + (size_t)node * 128 + lane * 8)     = o0;
    *(float4*)(out + (size_t)node * 128 + lane * 8 + 4) = o1;
}

// 256 thr = 32 groups x 8 lanes; one node per group; lane owns 8 of 64 feats.
__global__ __launch_bounds__(256)
void k_agg64(const ushort* __restrict__ Yb, const int* __restrict__ rowptr,
             const int* __restrict__ csrc, const float* __restrict__ nd,
             const float* __restrict__ bias, float* __restrict__ out) {
    int tid = threadIdx.x;
    int grp = tid >> 3;
    int lane = tid & 7;
    int node = blockIdx.x * 32 + grp;
    int beg = rowptr[node], end = rowptr[node + 1];
    float acc[8] = {0.f, 0.f, 0.f, 0.f, 0.f, 0.f, 0.f, 0.f};
    int e = beg;
    for (; e + 3 < end; e += 4) {
        int s0 = csrc[e];     int s1 = csrc[e + 1];
        int s2 = csrc[e + 2]; int s3 = csrc[e + 3];
        uint4 q0 = *(const uint4*)(Yb + (size_t)s0 * 64 + lane * 8);
        uint4 q1 = *(const uint4*)(Yb + (size_t)s1 * 64 + lane * 8);
        uint4 q2 = *(const uint4*)(Yb + (size_t)s2 * 64 + lane * 8);
        uint4 q3 = *(const uint4*)(Yb + (size_t)s3 * 64 + lane * 8);
        bf8_add(q0, acc); bf8_add(q1, acc); bf8_add(q2, acc); bf8_add(q3, acc);
    }
    for (; e < end; ++e) {
        uint4 q = *(const uint4*)(Yb + (size_t)csrc[e] * 64 + lane * 8);
        bf8_add(q, acc);
    }
    float ndv = nd[node];
    float4 b0 = *(const float4*)(bias + lane * 8);
    float4 b1 = *(const float4*)(bias + lane * 8 + 4);
    float4 o0, o1;
    o0.x = acc[0] * ndv + b0.x; o0.y = acc[1] * ndv + b0.y;
    o0.z = acc[2] * ndv + b0.z; o0.w = acc[3] * ndv + b0.w;
    o1.x = acc[4] * ndv + b1.x; o1.y = acc[5] * ndv + b1.y;
    o1.z = acc[6] * ndv + b1.z; o1.w = acc[7] * ndv + b1.w;
    *(float4*)(out + (size_t)node * 64 + lane * 8)     = o0;
    *(float4*)(out + (size_t)node * 64 + lane * 8 + 4) = o1;
}

// ---------------- launch ----------------

extern "C" void kernel_launch(void* const* d_in, const int* in_sizes, int n_in,
                              void* d_out, int out_size, void* d_ws, size_t ws_size,
                              hipStream_t stream) {
    const float* x  = (const float*)d_in[0];
    const int* esrc = (const int*)d_in[1];
    const int* edst = (const int*)d_in[2];
    const float* W0 = (const float*)d_in[3];
    const float* b0 = (const float*)d_in[4];
    const float* W1 = (const float*)d_in[5];
    const float* b1 = (const float*)d_in[6];
    const float* W2 = (const float*)d_in[7];
    const float* b2 = (const float*)d_in[8];
    float* out = (float*)d_out;

    // workspace (4-B units; ~27 MB). No trailing backslashes in comments.
    float* ns      = (float*)d_ws;                // NN
    float* nd      = ns + NN;                     // NN
    int*   csum    = (int*)(nd + NN);             // NN (in-degree totals)
    int*   cnt4    = csum + NN;                   // 8*NN (out:[0,4NN) in:[4NN,8NN))
    int*   cursor4 = cnt4 + 8 * NN;               // 4*NN (contiguous w/ cnt4: one memset)
    int*   rowptr  = cursor4 + 4 * NN;            // NN+8
    int*   rowptr4 = rowptr + NN + 8;             // 4*NN (16B-aligned for int4 store)
    int*   bsum    = rowptr4 + 4 * NN;            // 512
    int*   bsumex  = bsum + 512;                  // 512
    int*   csrc    = bsumex + 512;                // NE (src-only CSR)
    ushort* WT0    = (ushort*)(csrc + NE);        // 128*128 bf16
    ushort* WT1    = WT0 + 128 * 128;             // 128*128 bf16
    ushort* WT2    = WT1 + 128 * 128;             // 64*128 bf16
    ushort* Y2b    = WT2 + 64 * 128;              // NN*64 bf16 (16B-aligned)

    // output chunks
    float* h1 = out + (size_t)NN * 128;
    float* h2 = h1 + (size_t)NN * 128;
    float* h3 = h2 + (size_t)NN * 128;            // NN*64 floats

    // bf16 GEMM outputs parked in dead output slots (same lifetimes as round 6)
    ushort* Y0b = (ushort*)h2;                    // NN*128 bf16
    ushort* Y1b = (ushort*)h3;                    // NN*128 bf16

    // 1. zero replica counters + cursors (contiguous 12*NN ints)
    (void)hipMemsetAsync(cnt4, 0, (size_t)12 * NN * sizeof(int), stream);

    // 2. degrees (replicated) -> norms + in-degree totals
    k_deg<<<(NE + 255) / 256, 256, 0, stream>>>(esrc, edst, cnt4);
    k_norm<<<(NN + 255) / 256, 256, 0, stream>>>((const int4*)cnt4,
                                                 (const int4*)(cnt4 + 4 * NN),
                                                 ns, nd, csum);

    // 3. scan csum -> rowptr (+ per-replica sub-rowptr)
    k_blocksum<<<NB, 256, 0, stream>>>(csum, bsum);
    k_scanb<<<1, 512, 0, stream>>>(bsum, bsumex, rowptr);
    k_rowptr<<<NB, 256, 0, stream>>>(csum, (const int4*)(cnt4 + 4 * NN), bsumex,
                                     rowptr, (int4*)rowptr4);

    // 4. fill CSR (src only; replica cursors)
    k_fillcsr<<<(NE + 255) / 256, 256, 0, stream>>>(esrc, edst, rowptr4, cursor4, csrc);

    // 5. weight transposes (bf16)
    k_wt<128><<<64, 256, 0, stream>>>(W0, WT0);
    k_wt<128><<<64, 256, 0, stream>>>(W1, WT1);
    k_wt<64><<<32, 256, 0, stream>>>(W2, WT2);

    // 6. layer 1: Y0 = ns.(x@W0) (+fused x passthrough) -> agg -> h1
    k_gemm_mfma<2, 128, true><<<1024, 256, 0, stream>>>(x, WT0, ns, Y0b, out);
    k_agg128<true><<<NN / 16, 256, 0, stream>>>(Y0b, rowptr, csrc, nd, b0, h1);

    // 7. layer 2: Y1 = ns.(h1@W1) -> agg -> h2 (overwrites dead Y0b)
    k_gemm_mfma<2, 128, false><<<1024, 256, 0, stream>>>(h1, WT1, ns, Y1b, nullptr);
    k_agg128<true><<<NN / 16, 256, 0, stream>>>(Y1b, rowptr, csrc, nd, b1, h2);

    // 8. layer 3: Y2 = ns.(h2@W2) (128->64) -> agg -> h3 (overwrites dead Y1b)
    k_gemm_mfma<1, 64, false><<<1024, 256, 0, stream>>>(h2, WT2, ns, Y2b, nullptr);
    k_agg64<<<NN / 32, 256, 0, stream>>>(Y2b, rowptr, csrc, nd, b2, h3);
}

// Round 8
// 439.913 us; speedup vs baseline: 20.0195x; 1.1423x over previous
//
#include <hip/hip_runtime.h>

#define NN 100000
#define NE 1600000
#define NB 391      // ceil(NN/256)
#define RS 32768    // nodes per k-range
#define KR 4        // ranges (4*32768 >= NN)
#define RSL 64      // edge slices
#define SLICE 25000 // NE / RSL

typedef unsigned int uint;
typedef unsigned short ushort;
typedef unsigned char uchar;
typedef __attribute__((ext_vector_type(8))) short short8;   // 8 bf16 MFMA frag
typedef __attribute__((ext_vector_type(4))) float f32x4;    // MFMA acc

__device__ __forceinline__ ushort f2bf(float f) {      // RNE fp32 -> bf16
    uint u = __float_as_uint(f);
    return (ushort)((u + 0x7FFFu + ((u >> 16) & 1u)) >> 16);
}

// decode 8 bf16 from a uint4 and add into acc[8] (weights pre-folded into rows)
__device__ __forceinline__ void bf8_add(uint4 q, float* acc) {
    acc[0] += __uint_as_float(q.x << 16);
    acc[1] += __uint_as_float(q.x & 0xFFFF0000u);
    acc[2] += __uint_as_float(q.y << 16);
    acc[3] += __uint_as_float(q.y & 0xFFFF0000u);
    acc[4] += __uint_as_float(q.z << 16);
    acc[5] += __uint_as_float(q.z & 0xFFFF0000u);
    acc[6] += __uint_as_float(q.w << 16);
    acc[7] += __uint_as_float(q.w & 0xFFFF0000u);
}

// ---------------- LDS-privatized degree histograms (no global atomics) ----------
// Block (k,r): node range [k*RS,(k+1)*RS), edge slice [r*SLICE,(r+1)*SLICE).
// Byte-packed LDS counters (per-block per-byte count <= ~8, no carry risk).

__global__ __launch_bounds__(256)
void k_hist(const int* __restrict__ src, const int* __restrict__ dst,
            uchar* __restrict__ pout, uchar* __restrict__ pin) {
    int k = blockIdx.x >> 6, r = blockIdx.x & 63;
    __shared__ uint ho[RS / 4], hi[RS / 4];
    for (int i = threadIdx.x; i < RS / 4; i += 256) { ho[i] = 0; hi[i] = 0; }
    __syncthreads();
    int base = k * RS;
    int lo = r * SLICE, hiend = lo + SLICE;
    for (int i = lo + threadIdx.x; i < hiend; i += 256) {
        int s = src[i] - base;
        if ((uint)s < RS) atomicAdd(&ho[s >> 2], 1u << (8 * (s & 3)));
        int d = dst[i] - base;
        if ((uint)d < RS) atomicAdd(&hi[d >> 2], 1u << (8 * (d & 3)));
    }
    __syncthreads();
    uint* po = (uint*)(pout + ((size_t)k * RSL + r) * RS);
    uint* pi = (uint*)(pin + ((size_t)k * RSL + r) * RS);
    for (int i = threadIdx.x; i < RS / 4; i += 256) { po[i] = ho[i]; pi[i] = hi[i]; }
}

// ---------------- reduce partials -> norms/degrees; rewrite pin as r-prefix -----

__global__ void k_red(const uchar* __restrict__ pout, uchar* __restrict__ pin,
                      float* __restrict__ ns, float* __restrict__ nd,
                      int* __restrict__ csum) {
    int n = blockIdx.x * 256 + threadIdx.x;
    if (n >= NN) return;
    int k = n >> 15, j = n & (RS - 1);
    const uchar* po = pout + (size_t)k * RSL * RS + j;
    uchar* pi = pin + (size_t)k * RSL * RS + j;
    int so = 0;
    #pragma unroll
    for (int r = 0; r < RSL; ++r) so += po[(size_t)r * RS];
    int si = 0;
    #pragma unroll
    for (int r = 0; r < RSL; ++r) {
        uchar c = pi[(size_t)r * RS];
        pi[(size_t)r * RS] = (uchar)si;     // exclusive prefix along r
        si += c;
    }
    ns[n] = (so > 0) ? rsqrtf((float)so) : 0.f;
    nd[n] = (si > 0) ? rsqrtf((float)si) : 0.f;
    csum[n] = si;
}

// ---------------- exclusive scan of csum -> rowptr ----------------

__global__ void k_blocksum(const int* __restrict__ cnt, int* __restrict__ bsum) {
    __shared__ int s[256];
    int t = threadIdx.x;
    int i = blockIdx.x * 256 + t;
    s[t] = (i < NN) ? cnt[i] : 0;
    __syncthreads();
    for (int off = 128; off > 0; off >>= 1) {
        if (t < off) s[t] += s[t + off];
        __syncthreads();
    }
    if (t == 0) bsum[blockIdx.x] = s[0];
}

__global__ void k_scanb(const int* __restrict__ bsum, int* __restrict__ bsumex,
                        int* __restrict__ rowptr) {
    __shared__ int s[512];
    int t = threadIdx.x;
    int v = (t < NB) ? bsum[t] : 0;
    s[t] = v;
    __syncthreads();
    for (int off = 1; off < 512; off <<= 1) {
        int add = (t >= off) ? s[t - off] : 0;
        __syncthreads();
        s[t] += add;
        __syncthreads();
    }
    if (t < NB) bsumex[t] = s[t] - v;
    if (t == 0) rowptr[NN] = NE;
}

__global__ void k_rowptr(const int* __restrict__ cnt, const int* __restrict__ bsumex,
                         int* __restrict__ rowptr) {
    __shared__ int s[256];
    int t = threadIdx.x;
    int i = blockIdx.x * 256 + t;
    int v = (i < NN) ? cnt[i] : 0;
    s[t] = v;
    __syncthreads();
    for (int off = 1; off < 256; off <<= 1) {
        int add = (t >= off) ? s[t - off] : 0;
        __syncthreads();
        s[t] += add;
        __syncthreads();
    }
    if (i < NN) rowptr[i] = bsumex[blockIdx.x] + s[t] - v;
}

// ---------------- CSR fill via LDS cursors (no global atomics) ----------------
// Block (k,r): LDS cursors init'd to the r-prefix; packed 2 ushorts/uint.

__global__ __launch_bounds__(256)
void k_fill(const int* __restrict__ src, const int* __restrict__ dst,
            const uchar* __restrict__ pin, const int* __restrict__ rowptr,
            int* __restrict__ csrc) {
    int k = blockIdx.x >> 6, r = blockIdx.x & 63;
    __shared__ uint cur[RS / 2];
    const uchar* pi = pin + ((size_t)k * RSL + r) * RS;
    for (int i = threadIdx.x; i < RS / 2; i += 256) {
        uint a = pi[2 * i], b = pi[2 * i + 1];
        cur[i] = a | (b << 16);
    }
    __syncthreads();
    int base = k * RS;
    int lo = r * SLICE, hiend = lo + SLICE;
    for (int i = lo + threadIdx.x; i < hiend; i += 256) {
        int d = dst[i];
        int j = d - base;
        if ((uint)j < RS) {
            uint old = atomicAdd(&cur[j >> 1], 1u << (16 * (j & 1)));
            int p = (old >> (16 * (j & 1))) & 0xFFFF;
            csrc[rowptr[d] + p] = src[i];
        }
    }
}

// ---------------- W transpose -> bf16 (WT[n][k] = bf16(W[k][n])) ----------------

template<int N>
__global__ void k_wt(const float* __restrict__ W, ushort* __restrict__ WT) {
    int i = blockIdx.x * 256 + threadIdx.x;
    if (i < N * 128) {
        int n = i >> 7, k = i & 127;
        WT[i] = f2bf(W[k * N + n]);
    }
}

// ---------------- dense MFMA GEMM: Cb[M x N] = bf16(ns_row * (A @ W)) ------------
// 256 thr = 4 waves; B-frags in registers; grid-stride over 16-row groups.
// Frag layouts (guide §3, m89/m92): A/B lane l: 8 contiguous k at k=(l>>4)*8;
// C lane l reg r: row=(l>>4)*4+r, col=l&15.

template<int NT, int N, bool COPY>
__global__ __launch_bounds__(256)
void k_gemm_mfma(const float* __restrict__ A, const ushort* __restrict__ WT,
                 const float* __restrict__ ns, ushort* __restrict__ Cb,
                 float* __restrict__ xout) {
    int tid = threadIdx.x;
    int w = tid >> 6;
    int l = tid & 63;
    int li = l & 15;
    int kg = l >> 4;           // 0..3
    short8 bfrag[NT][4];
    #pragma unroll
    for (int n = 0; n < NT; ++n) {
        int col = w * 16 * NT + n * 16 + li;
        #pragma unroll
        for (int kt = 0; kt < 4; ++kt)
            bfrag[n][kt] = *(const short8*)(WT + (size_t)col * 128 + kt * 32 + kg * 8);
    }
    for (int mg = blockIdx.x; mg < NN / 16; mg += gridDim.x) {
        int row = mg * 16 + li;
        short8 afrag[4];
        #pragma unroll
        for (int kt = 0; kt < 4; ++kt) {
            const float* ap = A + (size_t)row * 128 + kt * 32 + kg * 8;
            float4 a0 = *(const float4*)ap;
            float4 a1 = *(const float4*)(ap + 4);
            if (COPY && w == 0) {   // fused x-passthrough (each tile covered once)
                float* op = xout + (size_t)row * 128 + kt * 32 + kg * 8;
                *(float4*)op = a0;
                *(float4*)(op + 4) = a1;
            }
            short8 af;
            af[0] = (short)f2bf(a0.x); af[1] = (short)f2bf(a0.y);
            af[2] = (short)f2bf(a0.z); af[3] = (short)f2bf(a0.w);
            af[4] = (short)f2bf(a1.x); af[5] = (short)f2bf(a1.y);
            af[6] = (short)f2bf(a1.z); af[7] = (short)f2bf(a1.w);
            afrag[kt] = af;
        }
        int crow = mg * 16 + kg * 4;
        float4 nsv = *(const float4*)(ns + crow);     // crow % 4 == 0
        float nsa[4] = {nsv.x, nsv.y, nsv.z, nsv.w};
        #pragma unroll
        for (int n = 0; n < NT; ++n) {
            f32x4 acc = {0.f, 0.f, 0.f, 0.f};
            #pragma unroll
            for (int kt = 0; kt < 4; ++kt)
                acc = __builtin_amdgcn_mfma_f32_16x16x32_bf16(afrag[kt], bfrag[n][kt], acc, 0, 0, 0);
            int ccol = w * 16 * NT + n * 16 + li;
            #pragma unroll
            for (int r = 0; r < 4; ++r)
                Cb[(size_t)(crow + r) * N + ccol] = f2bf(acc[r] * nsa[r]);
        }
    }
}

// ---------------- aggregation: out = [relu](nd * sum_e Yb[src_e] + bias) ---------
// 256 thr = 16 groups x 16 lanes; one node per group; lane owns 8 feats.

template<bool RELU>
__global__ __launch_bounds__(256)
void k_agg128(const ushort* __restrict__ Yb, const int* __restrict__ rowptr,
              const int* __restrict__ csrc, const float* __restrict__ nd,
              const float* __restrict__ bias, float* __restrict__ out) {
    int tid = threadIdx.x;
    int grp = tid >> 4;
    int lane = tid & 15;
    int node = blockIdx.x * 16 + grp;
    int beg = rowptr[node], end = rowptr[node + 1];
    float acc[8] = {0.f, 0.f, 0.f, 0.f, 0.f, 0.f, 0.f, 0.f};
    int e = beg;
    for (; e + 3 < end; e += 4) {              // 4 gathers in flight
        int s0 = csrc[e];     int s1 = csrc[e + 1];
        int s2 = csrc[e + 2]; int s3 = csrc[e + 3];
        uint4 q0 = *(const uint4*)(Yb + (size_t)s0 * 128 + lane * 8);
        uint4 q1 = *(const uint4*)(Yb + (size_t)s1 * 128 + lane * 8);
        uint4 q2 = *(const uint4*)(Yb + (size_t)s2 * 128 + lane * 8);
        uint4 q3 = *(const uint4*)(Yb + (size_t)s3 * 128 + lane * 8);
        bf8_add(q0, acc); bf8_add(q1, acc); bf8_add(q2, acc); bf8_add(q3, acc);
    }
    for (; e < end; ++e) {
        uint4 q = *(const uint4*)(Yb + (size_t)csrc[e] * 128 + lane * 8);
        bf8_add(q, acc);
    }
    float ndv = nd[node];
    float4 b0 = *(const float4*)(bias + lane * 8);
    float4 b1 = *(const float4*)(bias + lane * 8 + 4);
    float4 o0, o1;
    o0.x = acc[0] * ndv + b0.x; o0.y = acc[1] * ndv + b0.y;
    o0.z = acc[2] * ndv + b0.z; o0.w = acc[3] * ndv + b0.w;
    o1.x = acc[4] * ndv + b1.x; o1.y = acc[5] * ndv + b1.y;
    o1.z = acc[6] * ndv + b1.z; o1.w = acc[7] * ndv + b1.w;
    if (RELU) {
        o0.x = fmaxf(o0.x, 0.f); o0.y = fmaxf(o0.y, 0.f);
        o0.z = fmaxf(o0.z, 0.f); o0.w = fmaxf(o0.w, 0.f);
        o1.x = fmaxf(o1.x, 0.f); o1.y = fmaxf(o1.y, 0.f);
        o1.z = fmaxf(o1.z, 0.f); o1.w = fmaxf(o1.w, 0.f);
    }
    *(float4*)(out + (size_t)node * 128 + lane * 8)     = o0;
    *(float4*)(out + (size_t)node * 128 + lane * 8 + 4) = o1;
}

// 256 thr = 32 groups x 8 lanes; one node per group; lane owns 8 of 64 feats.
__global__ __launch_bounds__(256)
void k_agg64(const ushort* __restrict__ Yb, const int* __restrict__ rowptr,
             const int* __restrict__ csrc, const float* __restrict__ nd,
             const float* __restrict__ bias, float* __restrict__ out) {
    int tid = threadIdx.x;
    int grp = tid >> 3;
    int lane = tid & 7;
    int node = blockIdx.x * 32 + grp;
    int beg = rowptr[node], end = rowptr[node + 1];
    float acc[8] = {0.f, 0.f, 0.f, 0.f, 0.f, 0.f, 0.f, 0.f};
    int e = beg;
    for (; e + 3 < end; e += 4) {
        int s0 = csrc[e];     int s1 = csrc[e + 1];
        int s2 = csrc[e + 2]; int s3 = csrc[e + 3];
        uint4 q0 = *(const uint4*)(Yb + (size_t)s0 * 64 + lane * 8);
        uint4 q1 = *(const uint4*)(Yb + (size_t)s1 * 64 + lane * 8);
        uint4 q2 = *(const uint4*)(Yb + (size_t)s2 * 64 + lane * 8);
        uint4 q3 = *(const uint4*)(Yb + (size_t)s3 * 64 + lane * 8);
        bf8_add(q0, acc); bf8_add(q1, acc); bf8_add(q2, acc); bf8_add(q3, acc);
    }
    for (; e < end; ++e) {
        uint4 q = *(const uint4*)(Yb + (size_t)csrc[e] * 64 + lane * 8);
        bf8_add(q, acc);
    }
    float ndv = nd[node];
    float4 b0 = *(const float4*)(bias + lane * 8);
    float4 b1 = *(const float4*)(bias + lane * 8 + 4);
    float4 o0, o1;
    o0.x = acc[0] * ndv + b0.x; o0.y = acc[1] * ndv + b0.y;
    o0.z = acc[2] * ndv + b0.z; o0.w = acc[3] * ndv + b0.w;
    o1.x = acc[4] * ndv + b1.x; o1.y = acc[5] * ndv + b1.y;
    o1.z = acc[6] * ndv + b1.z; o1.w = acc[7] * ndv + b1.w;
    *(float4*)(out + (size_t)node * 64 + lane * 8)     = o0;
    *(float4*)(out + (size_t)node * 64 + lane * 8 + 4) = o1;
}

// ---------------- launch ----------------

extern "C" void kernel_launch(void* const* d_in, const int* in_sizes, int n_in,
                              void* d_out, int out_size, void* d_ws, size_t ws_size,
                              hipStream_t stream) {
    const float* x  = (const float*)d_in[0];
    const int* esrc = (const int*)d_in[1];
    const int* edst = (const int*)d_in[2];
    const float* W0 = (const float*)d_in[3];
    const float* b0 = (const float*)d_in[4];
    const float* W1 = (const float*)d_in[5];
    const float* b1 = (const float*)d_in[6];
    const float* W2 = (const float*)d_in[7];
    const float* b2 = (const float*)d_in[8];
    float* out = (float*)d_out;

    // workspace (~38 MB). No trailing backslashes in comments.
    float* ns      = (float*)d_ws;                // NN
    float* nd      = ns + NN;                     // NN
    int*   csum    = (int*)(nd + NN);             // NN
    int*   rowptr  = csum + NN;                   // NN+8
    int*   bsum    = rowptr + NN + 8;             // 512
    int*   bsumex  = bsum + 512;                  // 512
    int*   csrc    = bsumex + 512;                // NE
    uchar* pout    = (uchar*)(csrc + NE);         // KR*RSL*RS = 8 MB
    uchar* pin     = pout + (size_t)KR * RSL * RS;// 8 MB
    ushort* WT0    = (ushort*)(pin + (size_t)KR * RSL * RS);  // 128*128 bf16 (16B-aligned)
    ushort* WT1    = WT0 + 128 * 128;             // 128*128 bf16
    ushort* WT2    = WT1 + 128 * 128;             // 64*128 bf16
    ushort* Y2b    = WT2 + 64 * 128;              // NN*64 bf16

    // output chunks
    float* h1 = out + (size_t)NN * 128;
    float* h2 = h1 + (size_t)NN * 128;
    float* h3 = h2 + (size_t)NN * 128;            // NN*64 floats

    // bf16 GEMM outputs parked in dead output slots (lifetimes as round 6)
    ushort* Y0b = (ushort*)h2;                    // NN*128 bf16
    ushort* Y1b = (ushort*)h3;                    // NN*128 bf16

    // 1. degree histograms (LDS-privatized, no global atomics)
    k_hist<<<KR * RSL, 256, 0, stream>>>(esrc, edst, pout, pin);

    // 2. reduce -> ns/nd/csum; pin becomes per-(k,r) exclusive prefix
    k_red<<<(NN + 255) / 256, 256, 0, stream>>>(pout, pin, ns, nd, csum);

    // 3. scan csum -> rowptr
    k_blocksum<<<NB, 256, 0, stream>>>(csum, bsum);
    k_scanb<<<1, 512, 0, stream>>>(bsum, bsumex, rowptr);
    k_rowptr<<<NB, 256, 0, stream>>>(csum, bsumex, rowptr);

    // 4. fill CSR via LDS cursors (no global atomics)
    k_fill<<<KR * RSL, 256, 0, stream>>>(esrc, edst, pin, rowptr, csrc);

    // 5. weight transposes (bf16)
    k_wt<128><<<64, 256, 0, stream>>>(W0, WT0);
    k_wt<128><<<64, 256, 0, stream>>>(W1, WT1);
    k_wt<64><<<32, 256, 0, stream>>>(W2, WT2);

    // 6. layer 1: Y0 = ns.(x@W0) (+fused x passthrough) -> agg -> h1
    k_gemm_mfma<2, 128, true><<<1024, 256, 0, stream>>>(x, WT0, ns, Y0b, out);
    k_agg128<true><<<NN / 16, 256, 0, stream>>>(Y0b, rowptr, csrc, nd, b0, h1);

    // 7. layer 2: Y1 = ns.(h1@W1) -> agg -> h2 (overwrites dead Y0b)
    k_gemm_mfma<2, 128, false><<<1024, 256, 0, stream>>>(h1, WT1, ns, Y1b, nullptr);
    k_agg128<true><<<NN / 16, 256, 0, stream>>>(Y1b, rowptr, csrc, nd, b1, h2);

    // 8. layer 3: Y2 = ns.(h2@W2) (128->64) -> agg -> h3 (overwrites dead Y1b)
    k_gemm_mfma<1, 64, false><<<1024, 256, 0, stream>>>(h2, WT2, ns, Y2b, nullptr);
    k_agg64<<<NN / 32, 256, 0, stream>>>(Y2b, rowptr, csrc, nd, b2, h3);
}

// Round 9
// 436.374 us; speedup vs baseline: 20.1818x; 1.0081x over previous
//
#include <hip/hip_runtime.h>

#define NN 100000
#define NE 1600000
#define NB 391      // ceil(NN/256)
#define RS 32768    // nodes per k-range
#define KR 4        // ranges (4*32768 >= NN)
#define RSL 64      // edge slices
#define SLICE 25000 // NE / RSL

typedef unsigned int uint;
typedef unsigned short ushort;
typedef unsigned char uchar;
typedef __attribute__((ext_vector_type(8))) short short8;   // 8 bf16 MFMA frag
typedef __attribute__((ext_vector_type(4))) float f32x4;    // MFMA acc

__device__ __forceinline__ ushort f2bf(float f) {      // RNE fp32 -> bf16
    uint u = __float_as_uint(f);
    return (ushort)((u + 0x7FFFu + ((u >> 16) & 1u)) >> 16);
}

// decode 8 bf16 from a uint4 and add into acc[8]
__device__ __forceinline__ void bf8_add(uint4 q, float* acc) {
    acc[0] += __uint_as_float(q.x << 16);
    acc[1] += __uint_as_float(q.x & 0xFFFF0000u);
    acc[2] += __uint_as_float(q.y << 16);
    acc[3] += __uint_as_float(q.y & 0xFFFF0000u);
    acc[4] += __uint_as_float(q.z << 16);
    acc[5] += __uint_as_float(q.z & 0xFFFF0000u);
    acc[6] += __uint_as_float(q.w << 16);
    acc[7] += __uint_as_float(q.w & 0xFFFF0000u);
}

// ---------------- LDS-privatized degree histograms (no global atomics) ----------

__global__ __launch_bounds__(256)
void k_hist(const int* __restrict__ src, const int* __restrict__ dst,
            uchar* __restrict__ pout, uchar* __restrict__ pin) {
    int k = blockIdx.x >> 6, r = blockIdx.x & 63;
    __shared__ uint ho[RS / 4], hi[RS / 4];
    for (int i = threadIdx.x; i < RS / 4; i += 256) { ho[i] = 0; hi[i] = 0; }
    __syncthreads();
    int base = k * RS;
    int lo = r * SLICE, hiend = lo + SLICE;
    for (int i = lo + threadIdx.x; i < hiend; i += 256) {
        int s = src[i] - base;
        if ((uint)s < RS) atomicAdd(&ho[s >> 2], 1u << (8 * (s & 3)));
        int d = dst[i] - base;
        if ((uint)d < RS) atomicAdd(&hi[d >> 2], 1u << (8 * (d & 3)));
    }
    __syncthreads();
    uint* po = (uint*)(pout + ((size_t)k * RSL + r) * RS);
    uint* pi = (uint*)(pin + ((size_t)k * RSL + r) * RS);
    for (int i = threadIdx.x; i < RS / 4; i += 256) { po[i] = ho[i]; pi[i] = hi[i]; }
}

// ------- reduce partials -> norms/degrees; pin -> r-prefix; fused blocksum ------

__global__ __launch_bounds__(256)
void k_red(const uchar* __restrict__ pout, uchar* __restrict__ pin,
           float* __restrict__ ns, float* __restrict__ nd,
           int* __restrict__ csum, int* __restrict__ bsum) {
    __shared__ int sred[256];
    int t = threadIdx.x;
    int n = blockIdx.x * 256 + t;
    int si = 0;
    if (n < NN) {
        int k = n >> 15, j = n & (RS - 1);
        const uchar* po = pout + (size_t)k * RSL * RS + j;
        uchar* pi = pin + (size_t)k * RSL * RS + j;
        int so = 0;
        #pragma unroll
        for (int r = 0; r < RSL; ++r) so += po[(size_t)r * RS];
        #pragma unroll
        for (int r = 0; r < RSL; ++r) {
            uchar c = pi[(size_t)r * RS];
            pi[(size_t)r * RS] = (uchar)si;     // exclusive prefix along r
            si += c;
        }
        ns[n] = (so > 0) ? rsqrtf((float)so) : 0.f;
        nd[n] = (si > 0) ? rsqrtf((float)si) : 0.f;
        csum[n] = si;
    }
    sred[t] = si;
    __syncthreads();
    for (int off = 128; off > 0; off >>= 1) {
        if (t < off) sred[t] += sred[t + off];
        __syncthreads();
    }
    if (t == 0) bsum[blockIdx.x] = sred[0];
}

// ---------------- scan: block sums -> exclusive block offsets ----------------

__global__ void k_scanb(const int* __restrict__ bsum, int* __restrict__ bsumex,
                        int* __restrict__ rowptr) {
    __shared__ int s[512];
    int t = threadIdx.x;
    int v = (t < NB) ? bsum[t] : 0;
    s[t] = v;
    __syncthreads();
    for (int off = 1; off < 512; off <<= 1) {
        int add = (t >= off) ? s[t - off] : 0;
        __syncthreads();
        s[t] += add;
        __syncthreads();
    }
    if (t < NB) bsumex[t] = s[t] - v;
    if (t == 0) rowptr[NN] = NE;
}

__global__ void k_rowptr(const int* __restrict__ cnt, const int* __restrict__ bsumex,
                         int* __restrict__ rowptr) {
    __shared__ int s[256];
    int t = threadIdx.x;
    int i = blockIdx.x * 256 + t;
    int v = (i < NN) ? cnt[i] : 0;
    s[t] = v;
    __syncthreads();
    for (int off = 1; off < 256; off <<= 1) {
        int add = (t >= off) ? s[t - off] : 0;
        __syncthreads();
        s[t] += add;
        __syncthreads();
    }
    if (i < NN) rowptr[i] = bsumex[blockIdx.x] + s[t] - v;
}

// ---------------- CSR fill via LDS cursors (no global atomics) ----------------

__global__ __launch_bounds__(256)
void k_fill(const int* __restrict__ src, const int* __restrict__ dst,
            const uchar* __restrict__ pin, const int* __restrict__ rowptr,
            int* __restrict__ csrc) {
    int k = blockIdx.x >> 6, r = blockIdx.x & 63;
    __shared__ uint cur[RS / 2];
    const uchar* pi = pin + ((size_t)k * RSL + r) * RS;
    for (int i = threadIdx.x; i < RS / 2; i += 256) {
        uint a = pi[2 * i], b = pi[2 * i + 1];
        cur[i] = a | (b << 16);
    }
    __syncthreads();
    int base = k * RS;
    int lo = r * SLICE, hiend = lo + SLICE;
    for (int i = lo + threadIdx.x; i < hiend; i += 256) {
        int d = dst[i];
        int j = d - base;
        if ((uint)j < RS) {
            uint old = atomicAdd(&cur[j >> 1], 1u << (16 * (j & 1)));
            int p = (old >> (16 * (j & 1))) & 0xFFFF;
            csrc[rowptr[d] + p] = src[i];
        }
    }
}

// ------------- all W transposes -> bf16, one kernel (WT[n][k]=bf16(W[k][n])) -----

__global__ void k_wtall(const float* __restrict__ W0, const float* __restrict__ W1,
                        const float* __restrict__ W2, ushort* __restrict__ WT) {
    int i = blockIdx.x * 256 + threadIdx.x;      // 40960 total
    if (i < 16384) {
        int n = i >> 7, k = i & 127;
        WT[i] = f2bf(W0[k * 128 + n]);
    } else if (i < 32768) {
        int j = i - 16384; int n = j >> 7, k = j & 127;
        WT[i] = f2bf(W1[k * 128 + n]);
    } else if (i < 40960) {
        int j = i - 32768; int n = j >> 7, k = j & 127;
        WT[i] = f2bf(W2[k * 64 + n]);
    }
}

// ---------------- x passthrough + bf16 conversion ----------------

__global__ void k_xcvt(const float4* __restrict__ x, float4* __restrict__ out,
                       ushort* __restrict__ xb, int n4) {
    int i = blockIdx.x * blockDim.x + threadIdx.x;
    if (i < n4) {
        float4 v = x[i];
        out[i] = v;
        ushort4 b;
        b.x = f2bf(v.x); b.y = f2bf(v.y); b.z = f2bf(v.z); b.w = f2bf(v.w);
        *(ushort4*)(xb + (size_t)i * 4) = b;
    }
}

// ---------------- dense MFMA GEMM: Cb[M x N] = bf16(ns_row * (Ab @ W)) -----------
// A already bf16 -> pure short8 loads + MFMA, no conversion VALU.
// Frag layouts (guide §3, m89/m92): A/B lane l: 8 contiguous k at k=(l>>4)*8;
// C lane l reg r: row=(l>>4)*4+r, col=l&15.

template<int NT, int N>
__global__ __launch_bounds__(256)
void k_gemm_mfma(const ushort* __restrict__ Ab, const ushort* __restrict__ WT,
                 const float* __restrict__ ns, ushort* __restrict__ Cb) {
    int tid = threadIdx.x;
    int w = tid >> 6;
    int l = tid & 63;
    int li = l & 15;
    int kg = l >> 4;           // 0..3
    short8 bfrag[NT][4];
    #pragma unroll
    for (int n = 0; n < NT; ++n) {
        int col = w * 16 * NT + n * 16 + li;
        #pragma unroll
        for (int kt = 0; kt < 4; ++kt)
            bfrag[n][kt] = *(const short8*)(WT + (size_t)col * 128 + kt * 32 + kg * 8);
    }
    for (int mg = blockIdx.x; mg < NN / 16; mg += gridDim.x) {
        int row = mg * 16 + li;
        short8 afrag[4];
        #pragma unroll
        for (int kt = 0; kt < 4; ++kt)
            afrag[kt] = *(const short8*)(Ab + (size_t)row * 128 + kt * 32 + kg * 8);
        int crow = mg * 16 + kg * 4;
        float4 nsv = *(const float4*)(ns + crow);     // crow % 4 == 0
        float nsa[4] = {nsv.x, nsv.y, nsv.z, nsv.w};
        #pragma unroll
        for (int n = 0; n < NT; ++n) {
            f32x4 acc = {0.f, 0.f, 0.f, 0.f};
            #pragma unroll
            for (int kt = 0; kt < 4; ++kt)
                acc = __builtin_amdgcn_mfma_f32_16x16x32_bf16(afrag[kt], bfrag[n][kt], acc, 0, 0, 0);
            int ccol = w * 16 * NT + n * 16 + li;
            #pragma unroll
            for (int r = 0; r < 4; ++r)
                Cb[(size_t)(crow + r) * N + ccol] = f2bf(acc[r] * nsa[r]);
        }
    }
}

// --------- aggregation: h = relu(nd * sum Yb[src] + b); also emit bf16(h) --------
// 256 thr = 16 groups x 16 lanes; one node per group; lane owns 8 feats.

template<bool RELU>
__global__ __launch_bounds__(256)
void k_agg128(const ushort* __restrict__ Yb, const int* __restrict__ rowptr,
              const int* __restrict__ csrc, const float* __restrict__ nd,
              const float* __restrict__ bias, float* __restrict__ out,
              ushort* __restrict__ outb) {
    int tid = threadIdx.x;
    int grp = tid >> 4;
    int lane = tid & 15;
    int node = blockIdx.x * 16 + grp;
    int beg = rowptr[node], end = rowptr[node + 1];
    float acc[8] = {0.f, 0.f, 0.f, 0.f, 0.f, 0.f, 0.f, 0.f};
    int e = beg;
    for (; e + 7 < end; e += 8) {              // 8 gathers in flight
        int s0 = csrc[e];     int s1 = csrc[e + 1];
        int s2 = csrc[e + 2]; int s3 = csrc[e + 3];
        int s4 = csrc[e + 4]; int s5 = csrc[e + 5];
        int s6 = csrc[e + 6]; int s7 = csrc[e + 7];
        uint4 q0 = *(const uint4*)(Yb + (size_t)s0 * 128 + lane * 8);
        uint4 q1 = *(const uint4*)(Yb + (size_t)s1 * 128 + lane * 8);
        uint4 q2 = *(const uint4*)(Yb + (size_t)s2 * 128 + lane * 8);
        uint4 q3 = *(const uint4*)(Yb + (size_t)s3 * 128 + lane * 8);
        uint4 q4 = *(const uint4*)(Yb + (size_t)s4 * 128 + lane * 8);
        uint4 q5 = *(const uint4*)(Yb + (size_t)s5 * 128 + lane * 8);
        uint4 q6 = *(const uint4*)(Yb + (size_t)s6 * 128 + lane * 8);
        uint4 q7 = *(const uint4*)(Yb + (size_t)s7 * 128 + lane * 8);
        bf8_add(q0, acc); bf8_add(q1, acc); bf8_add(q2, acc); bf8_add(q3, acc);
        bf8_add(q4, acc); bf8_add(q5, acc); bf8_add(q6, acc); bf8_add(q7, acc);
    }
    for (; e + 3 < end; e += 4) {
        int s0 = csrc[e];     int s1 = csrc[e + 1];
        int s2 = csrc[e + 2]; int s3 = csrc[e + 3];
        uint4 q0 = *(const uint4*)(Yb + (size_t)s0 * 128 + lane * 8);
        uint4 q1 = *(const uint4*)(Yb + (size_t)s1 * 128 + lane * 8);
        uint4 q2 = *(const uint4*)(Yb + (size_t)s2 * 128 + lane * 8);
        uint4 q3 = *(const uint4*)(Yb + (size_t)s3 * 128 + lane * 8);
        bf8_add(q0, acc); bf8_add(q1, acc); bf8_add(q2, acc); bf8_add(q3, acc);
    }
    for (; e < end; ++e) {
        uint4 q = *(const uint4*)(Yb + (size_t)csrc[e] * 128 + lane * 8);
        bf8_add(q, acc);
    }
    float ndv = nd[node];
    float4 b0 = *(const float4*)(bias + lane * 8);
    float4 b1 = *(const float4*)(bias + lane * 8 + 4);
    float o[8];
    o[0] = acc[0] * ndv + b0.x; o[1] = acc[1] * ndv + b0.y;
    o[2] = acc[2] * ndv + b0.z; o[3] = acc[3] * ndv + b0.w;
    o[4] = acc[4] * ndv + b1.x; o[5] = acc[5] * ndv + b1.y;
    o[6] = acc[6] * ndv + b1.z; o[7] = acc[7] * ndv + b1.w;
    if (RELU) {
        #pragma unroll
        for (int i = 0; i < 8; ++i) o[i] = fmaxf(o[i], 0.f);
    }
    *(float4*)(out + (size_t)node * 128 + lane * 8)     = make_float4(o[0], o[1], o[2], o[3]);
    *(float4*)(out + (size_t)node * 128 + lane * 8 + 4) = make_float4(o[4], o[5], o[6], o[7]);
    short8 ob;
    #pragma unroll
    for (int i = 0; i < 8; ++i) ob[i] = (short)f2bf(o[i]);
    *(short8*)(outb + (size_t)node * 128 + lane * 8) = ob;
}

// 256 thr = 32 groups x 8 lanes; one node per group; lane owns 8 of 64 feats.
__global__ __launch_bounds__(256)
void k_agg64(const ushort* __restrict__ Yb, const int* __restrict__ rowptr,
             const int* __restrict__ csrc, const float* __restrict__ nd,
             const float* __restrict__ bias, float* __restrict__ out) {
    int tid = threadIdx.x;
    int grp = tid >> 3;
    int lane = tid & 7;
    int node = blockIdx.x * 32 + grp;
    int beg = rowptr[node], end = rowptr[node + 1];
    float acc[8] = {0.f, 0.f, 0.f, 0.f, 0.f, 0.f, 0.f, 0.f};
    int e = beg;
    for (; e + 7 < end; e += 8) {
        int s0 = csrc[e];     int s1 = csrc[e + 1];
        int s2 = csrc[e + 2]; int s3 = csrc[e + 3];
        int s4 = csrc[e + 4]; int s5 = csrc[e + 5];
        int s6 = csrc[e + 6]; int s7 = csrc[e + 7];
        uint4 q0 = *(const uint4*)(Yb + (size_t)s0 * 64 + lane * 8);
        uint4 q1 = *(const uint4*)(Yb + (size_t)s1 * 64 + lane * 8);
        uint4 q2 = *(const uint4*)(Yb + (size_t)s2 * 64 + lane * 8);
        uint4 q3 = *(const uint4*)(Yb + (size_t)s3 * 64 + lane * 8);
        uint4 q4 = *(const uint4*)(Yb + (size_t)s4 * 64 + lane * 8);
        uint4 q5 = *(const uint4*)(Yb + (size_t)s5 * 64 + lane * 8);
        uint4 q6 = *(const uint4*)(Yb + (size_t)s6 * 64 + lane * 8);
        uint4 q7 = *(const uint4*)(Yb + (size_t)s7 * 64 + lane * 8);
        bf8_add(q0, acc); bf8_add(q1, acc); bf8_add(q2, acc); bf8_add(q3, acc);
        bf8_add(q4, acc); bf8_add(q5, acc); bf8_add(q6, acc); bf8_add(q7, acc);
    }
    for (; e + 3 < end; e += 4) {
        int s0 = csrc[e];     int s1 = csrc[e + 1];
        int s2 = csrc[e + 2]; int s3 = csrc[e + 3];
        uint4 q0 = *(const uint4*)(Yb + (size_t)s0 * 64 + lane * 8);
        uint4 q1 = *(const uint4*)(Yb + (size_t)s1 * 64 + lane * 8);
        uint4 q2 = *(const uint4*)(Yb + (size_t)s2 * 64 + lane * 8);
        uint4 q3 = *(const uint4*)(Yb + (size_t)s3 * 64 + lane * 8);
        bf8_add(q0, acc); bf8_add(q1, acc); bf8_add(q2, acc); bf8_add(q3, acc);
    }
    for (; e < end; ++e) {
        uint4 q = *(const uint4*)(Yb + (size_t)csrc[e] * 64 + lane * 8);
        bf8_add(q, acc);
    }
    float ndv = nd[node];
    float4 b0 = *(const float4*)(bias + lane * 8);
    float4 b1 = *(const float4*)(bias + lane * 8 + 4);
    float4 o0, o1;
    o0.x = acc[0] * ndv + b0.x; o0.y = acc[1] * ndv + b0.y;
    o0.z = acc[2] * ndv + b0.z; o0.w = acc[3] * ndv + b0.w;
    o1.x = acc[4] * ndv + b1.x; o1.y = acc[5] * ndv + b1.y;
    o1.z = acc[6] * ndv + b1.z; o1.w = acc[7] * ndv + b1.w;
    *(float4*)(out + (size_t)node * 64 + lane * 8)     = o0;
    *(float4*)(out + (size_t)node * 64 + lane * 8 + 4) = o1;
}

// ---------------- launch ----------------

extern "C" void kernel_launch(void* const* d_in, const int* in_sizes, int n_in,
                              void* d_out, int out_size, void* d_ws, size_t ws_size,
                              hipStream_t stream) {
    const float* x  = (const float*)d_in[0];
    const int* esrc = (const int*)d_in[1];
    const int* edst = (const int*)d_in[2];
    const float* W0 = (const float*)d_in[3];
    const float* b0 = (const float*)d_in[4];
    const float* W1 = (const float*)d_in[5];
    const float* b1 = (const float*)d_in[6];
    const float* W2 = (const float*)d_in[7];
    const float* b2 = (const float*)d_in[8];
    float* out = (float*)d_out;

    // workspace (~115 MB; ws is ~716 MB). No trailing backslashes in comments.
    float* ns      = (float*)d_ws;                // NN
    float* nd      = ns + NN;                     // NN
    int*   csum    = (int*)(nd + NN);             // NN
    int*   rowptr  = csum + NN;                   // NN+8
    int*   bsum    = rowptr + NN + 8;             // 512
    int*   bsumex  = bsum + 512;                  // 512
    int*   csrc    = bsumex + 512;                // NE
    uchar* pout    = (uchar*)(csrc + NE);         // KR*RSL*RS = 8 MB
    uchar* pin     = pout + (size_t)KR * RSL * RS;// 8 MB
    ushort* WT0    = (ushort*)(pin + (size_t)KR * RSL * RS);  // 128*128
    ushort* WT1    = WT0 + 128 * 128;             // 128*128
    ushort* WT2    = WT1 + 128 * 128;             // 64*128
    ushort* Y2b    = WT2 + 64 * 128;              // NN*64
    ushort* xb     = Y2b + (size_t)NN * 64;       // NN*128 bf16
    ushort* h1b    = xb + (size_t)NN * 128;       // NN*128 bf16
    ushort* h2b    = h1b + (size_t)NN * 128;      // NN*128 bf16

    // output chunks
    float* h1 = out + (size_t)NN * 128;
    float* h2 = h1 + (size_t)NN * 128;
    float* h3 = h2 + (size_t)NN * 128;            // NN*64 floats

    // bf16 GEMM outputs parked in dead output slots (lifetimes as before)
    ushort* Y0b = (ushort*)h2;                    // NN*128 bf16
    ushort* Y1b = (ushort*)h3;                    // NN*128 bf16

    // 1. degree histograms (LDS-privatized, no global atomics)
    k_hist<<<KR * RSL, 256, 0, stream>>>(esrc, edst, pout, pin);

    // 2. reduce -> ns/nd/csum (+fused block sums); pin becomes r-prefix
    k_red<<<NB, 256, 0, stream>>>(pout, pin, ns, nd, csum, bsum);

    // 3. scan -> rowptr
    k_scanb<<<1, 512, 0, stream>>>(bsum, bsumex, rowptr);
    k_rowptr<<<NB, 256, 0, stream>>>(csum, bsumex, rowptr);

    // 4. fill CSR via LDS cursors (no global atomics)
    k_fill<<<KR * RSL, 256, 0, stream>>>(esrc, edst, pin, rowptr, csrc);

    // 5. weight transposes (one kernel)
    k_wtall<<<160, 256, 0, stream>>>(W0, W1, W2, WT0);

    // 6. x passthrough + bf16 conversion
    k_xcvt<<<(NN * 32 + 255) / 256, 256, 0, stream>>>((const float4*)x, (float4*)out,
                                                      xb, NN * 32);

    // 7. layer 1: Y0 = ns.(x@W0) -> agg -> h1 (+h1b)
    k_gemm_mfma<2, 128><<<1024, 256, 0, stream>>>(xb, WT0, ns, Y0b);
    k_agg128<true><<<NN / 16, 256, 0, stream>>>(Y0b, rowptr, csrc, nd, b0, h1, h1b);

    // 8. layer 2: Y1 = ns.(h1@W1) -> agg -> h2 (+h2b; overwrites dead Y0b)
    k_gemm_mfma<2, 128><<<1024, 256, 0, stream>>>(h1b, WT1, ns, Y1b);
    k_agg128<true><<<NN / 16, 256, 0, stream>>>(Y1b, rowptr, csrc, nd, b1, h2, h2b);

    // 9. layer 3: Y2 = ns.(h2@W2) (128->64) -> agg -> h3 (overwrites dead Y1b)
    k_gemm_mfma<1, 64><<<1024, 256, 0, stream>>>(h2b, WT2, ns, Y2b);
    k_agg64<<<NN / 32, 256, 0, stream>>>(Y2b, rowptr, csrc, nd, b2, h3);
}

// Round 10
// 387.092 us; speedup vs baseline: 22.7513x; 1.1273x over previous
//
#include <hip/hip_runtime.h>

#define NN 100000
#define NE 1600000
#define NB 391      // ceil(NN/256)
#define RS 32768    // nodes per k-range
#define KR 4        // ranges (4*32768 >= NN)
#define RSL 64      // edge slices
#define SLICE 25000 // NE / RSL

typedef unsigned int uint;
typedef unsigned short ushort;
typedef unsigned char uchar;
typedef __attribute__((ext_vector_type(8))) short short8;   // 8 bf16 MFMA frag
typedef __attribute__((ext_vector_type(4))) float f32x4;    // MFMA acc

__device__ __forceinline__ ushort f2bf(float f) {      // RNE fp32 -> bf16
    uint u = __float_as_uint(f);
    return (ushort)((u + 0x7FFFu + ((u >> 16) & 1u)) >> 16);
}

// decode 8 bf16 from a uint4 and add into acc[8]
__device__ __forceinline__ void bf8_add(uint4 q, float* acc) {
    acc[0] += __uint_as_float(q.x << 16);
    acc[1] += __uint_as_float(q.x & 0xFFFF0000u);
    acc[2] += __uint_as_float(q.y << 16);
    acc[3] += __uint_as_float(q.y & 0xFFFF0000u);
    acc[4] += __uint_as_float(q.z << 16);
    acc[5] += __uint_as_float(q.z & 0xFFFF0000u);
    acc[6] += __uint_as_float(q.w << 16);
    acc[7] += __uint_as_float(q.w & 0xFFFF0000u);
}

// ---------------- LDS-privatized degree histograms (no global atomics) ----------

__global__ __launch_bounds__(256)
void k_hist(const int* __restrict__ src, const int* __restrict__ dst,
            uchar* __restrict__ pout, uchar* __restrict__ pin) {
    int k = blockIdx.x >> 6, r = blockIdx.x & 63;
    __shared__ uint ho[RS / 4], hi[RS / 4];
    for (int i = threadIdx.x; i < RS / 4; i += 256) { ho[i] = 0; hi[i] = 0; }
    __syncthreads();
    int base = k * RS;
    int lo = r * SLICE, hiend = lo + SLICE;
    for (int i = lo + threadIdx.x; i < hiend; i += 256) {
        int s = src[i] - base;
        if ((uint)s < RS) atomicAdd(&ho[s >> 2], 1u << (8 * (s & 3)));
        int d = dst[i] - base;
        if ((uint)d < RS) atomicAdd(&hi[d >> 2], 1u << (8 * (d & 3)));
    }
    __syncthreads();
    uint* po = (uint*)(pout + ((size_t)k * RSL + r) * RS);
    uint* pi = (uint*)(pin + ((size_t)k * RSL + r) * RS);
    for (int i = threadIdx.x; i < RS / 4; i += 256) { po[i] = ho[i]; pi[i] = hi[i]; }
}

// ------- reduce partials -> norms/degrees; pin -> r-prefix; fused blocksum ------

__global__ __launch_bounds__(256)
void k_red(const uchar* __restrict__ pout, uchar* __restrict__ pin,
           float* __restrict__ ns, float* __restrict__ nd,
           int* __restrict__ csum, int* __restrict__ bsum) {
    __shared__ int sred[256];
    int t = threadIdx.x;
    int n = blockIdx.x * 256 + t;
    int si = 0;
    if (n < NN) {
        int k = n >> 15, j = n & (RS - 1);
        const uchar* po = pout + (size_t)k * RSL * RS + j;
        uchar* pi = pin + (size_t)k * RSL * RS + j;
        int so = 0;
        #pragma unroll
        for (int r = 0; r < RSL; ++r) so += po[(size_t)r * RS];
        #pragma unroll
        for (int r = 0; r < RSL; ++r) {
            uchar c = pi[(size_t)r * RS];
            pi[(size_t)r * RS] = (uchar)si;     // exclusive prefix along r
            si += c;
        }
        ns[n] = (so > 0) ? rsqrtf((float)so) : 0.f;
        nd[n] = (si > 0) ? rsqrtf((float)si) : 0.f;
        csum[n] = si;
    }
    sred[t] = si;
    __syncthreads();
    for (int off = 128; off > 0; off >>= 1) {
        if (t < off) sred[t] += sred[t + off];
        __syncthreads();
    }
    if (t == 0) bsum[blockIdx.x] = sred[0];
}

// ---------------- scan: block sums -> exclusive block offsets ----------------

__global__ void k_scanb(const int* __restrict__ bsum, int* __restrict__ bsumex,
                        int* __restrict__ rowptr) {
    __shared__ int s[512];
    int t = threadIdx.x;
    int v = (t < NB) ? bsum[t] : 0;
    s[t] = v;
    __syncthreads();
    for (int off = 1; off < 512; off <<= 1) {
        int add = (t >= off) ? s[t - off] : 0;
        __syncthreads();
        s[t] += add;
        __syncthreads();
    }
    if (t < NB) bsumex[t] = s[t] - v;
    if (t == 0) rowptr[NN] = NE;
}

__global__ void k_rowptr(const int* __restrict__ cnt, const int* __restrict__ bsumex,
                         int* __restrict__ rowptr) {
    __shared__ int s[256];
    int t = threadIdx.x;
    int i = blockIdx.x * 256 + t;
    int v = (i < NN) ? cnt[i] : 0;
    s[t] = v;
    __syncthreads();
    for (int off = 1; off < 256; off <<= 1) {
        int add = (t >= off) ? s[t - off] : 0;
        __syncthreads();
        s[t] += add;
        __syncthreads();
    }
    if (i < NN) rowptr[i] = bsumex[blockIdx.x] + s[t] - v;
}

// ---------------- CSR fill via LDS cursors (no global atomics) ----------------

__global__ __launch_bounds__(256)
void k_fill(const int* __restrict__ src, const int* __restrict__ dst,
            const uchar* __restrict__ pin, const int* __restrict__ rowptr,
            int* __restrict__ csrc) {
    int k = blockIdx.x >> 6, r = blockIdx.x & 63;
    __shared__ uint cur[RS / 2];
    const uchar* pi = pin + ((size_t)k * RSL + r) * RS;
    for (int i = threadIdx.x; i < RS / 2; i += 256) {
        uint a = pi[2 * i], b = pi[2 * i + 1];
        cur[i] = a | (b << 16);
    }
    __syncthreads();
    int base = k * RS;
    int lo = r * SLICE, hiend = lo + SLICE;
    for (int i = lo + threadIdx.x; i < hiend; i += 256) {
        int d = dst[i];
        int j = d - base;
        if ((uint)j < RS) {
            uint old = atomicAdd(&cur[j >> 1], 1u << (16 * (j & 1)));
            int p = (old >> (16 * (j & 1))) & 0xFFFF;
            csrc[rowptr[d] + p] = src[i];
        }
    }
}

// ------------- all W transposes -> bf16, one kernel (WT[n][k]=bf16(W[k][n])) -----

__global__ void k_wtall(const float* __restrict__ W0, const float* __restrict__ W1,
                        const float* __restrict__ W2, ushort* __restrict__ WT) {
    int i = blockIdx.x * 256 + threadIdx.x;      // 40960 total
    if (i < 16384) {
        int n = i >> 7, k = i & 127;
        WT[i] = f2bf(W0[k * 128 + n]);
    } else if (i < 32768) {
        int j = i - 16384; int n = j >> 7, k = j & 127;
        WT[i] = f2bf(W1[k * 128 + n]);
    } else if (i < 40960) {
        int j = i - 32768; int n = j >> 7, k = j & 127;
        WT[i] = f2bf(W2[k * 64 + n]);
    }
}

// -------- layer-1 GEMM: Y0b = bf16(ns*(x@W0)); wave0 also copies x -> out0 -------
// Frag layouts (guide §3, m89/m92): A/B lane l: 8 contiguous k at k=(l>>4)*8;
// C lane l reg r: row=(l>>4)*4+r, col=l&15.

__global__ __launch_bounds__(256)
void k_gemm1(const float* __restrict__ A, const ushort* __restrict__ WT,
             const float* __restrict__ ns, ushort* __restrict__ Cb,
             float* __restrict__ xout) {
    int tid = threadIdx.x;
    int w = tid >> 6;
    int l = tid & 63;
    int li = l & 15;
    int kg = l >> 4;           // 0..3
    short8 bfrag[2][4];
    #pragma unroll
    for (int n = 0; n < 2; ++n) {
        int col = w * 32 + n * 16 + li;
        #pragma unroll
        for (int kt = 0; kt < 4; ++kt)
            bfrag[n][kt] = *(const short8*)(WT + (size_t)col * 128 + kt * 32 + kg * 8);
    }
    for (int mg = blockIdx.x; mg < NN / 16; mg += gridDim.x) {
        int row = mg * 16 + li;
        short8 afrag[4];
        #pragma unroll
        for (int kt = 0; kt < 4; ++kt) {
            const float* ap = A + (size_t)row * 128 + kt * 32 + kg * 8;
            float4 a0 = *(const float4*)ap;
            float4 a1 = *(const float4*)(ap + 4);
            if (w == 0) {   // fused x-passthrough (each tile covered once)
                float* op = xout + (size_t)row * 128 + kt * 32 + kg * 8;
                *(float4*)op = a0;
                *(float4*)(op + 4) = a1;
            }
            short8 af;
            af[0] = (short)f2bf(a0.x); af[1] = (short)f2bf(a0.y);
            af[2] = (short)f2bf(a0.z); af[3] = (short)f2bf(a0.w);
            af[4] = (short)f2bf(a1.x); af[5] = (short)f2bf(a1.y);
            af[6] = (short)f2bf(a1.z); af[7] = (short)f2bf(a1.w);
            afrag[kt] = af;
        }
        int crow = mg * 16 + kg * 4;
        float4 nsv = *(const float4*)(ns + crow);     // crow % 4 == 0
        float nsa[4] = {nsv.x, nsv.y, nsv.z, nsv.w};
        #pragma unroll
        for (int n = 0; n < 2; ++n) {
            f32x4 acc = {0.f, 0.f, 0.f, 0.f};
            #pragma unroll
            for (int kt = 0; kt < 4; ++kt)
                acc = __builtin_amdgcn_mfma_f32_16x16x32_bf16(afrag[kt], bfrag[n][kt], acc, 0, 0, 0);
            int ccol = w * 32 + n * 16 + li;
            #pragma unroll
            for (int r = 0; r < 4; ++r)
                Cb[(size_t)(crow + r) * 128 + ccol] = f2bf(acc[r] * nsa[r]);
        }
    }
}

// ------- fused agg + next-layer GEMM -------------------------------------------
// Phase 1: h = relu(nd * sum_e Yb[src_e] + b)  (16 nodes/block, fp32 out,
//          bf16 copy staged in padded LDS tile).
// Phase 2: Yout = bf16(ns * (h @ W))  via MFMA, A from LDS, B from L2-hot WT.
// NOUT in {128, 64}; NT = NOUT/64 cols-of-16 per wave.

template<int NOUT>
__global__ __launch_bounds__(256)
void k_agg_gemm(const ushort* __restrict__ Yb, const int* __restrict__ rowptr,
                const int* __restrict__ csrc, const float* __restrict__ nd,
                const float* __restrict__ bias, const float* __restrict__ ns,
                const ushort* __restrict__ WT, float* __restrict__ hout,
                ushort* __restrict__ Yout) {
    constexpr int NT = NOUT / 64;
    __shared__ ushort sA[16][136];      // +8 bf16 pad breaks bank alignment
    int tid = threadIdx.x;
    int grp = tid >> 4;
    int lane = tid & 15;
    int node_base = blockIdx.x * 16;
    int node = node_base + grp;
    int beg = rowptr[node], end = rowptr[node + 1];
    float acc[8] = {0.f, 0.f, 0.f, 0.f, 0.f, 0.f, 0.f, 0.f};
    int e = beg;
    for (; e + 7 < end; e += 8) {              // 8 gathers in flight
        int s0 = csrc[e];     int s1 = csrc[e + 1];
        int s2 = csrc[e + 2]; int s3 = csrc[e + 3];
        int s4 = csrc[e + 4]; int s5 = csrc[e + 5];
        int s6 = csrc[e + 6]; int s7 = csrc[e + 7];
        uint4 q0 = *(const uint4*)(Yb + (size_t)s0 * 128 + lane * 8);
        uint4 q1 = *(const uint4*)(Yb + (size_t)s1 * 128 + lane * 8);
        uint4 q2 = *(const uint4*)(Yb + (size_t)s2 * 128 + lane * 8);
        uint4 q3 = *(const uint4*)(Yb + (size_t)s3 * 128 + lane * 8);
        uint4 q4 = *(const uint4*)(Yb + (size_t)s4 * 128 + lane * 8);
        uint4 q5 = *(const uint4*)(Yb + (size_t)s5 * 128 + lane * 8);
        uint4 q6 = *(const uint4*)(Yb + (size_t)s6 * 128 + lane * 8);
        uint4 q7 = *(const uint4*)(Yb + (size_t)s7 * 128 + lane * 8);
        bf8_add(q0, acc); bf8_add(q1, acc); bf8_add(q2, acc); bf8_add(q3, acc);
        bf8_add(q4, acc); bf8_add(q5, acc); bf8_add(q6, acc); bf8_add(q7, acc);
    }
    for (; e + 3 < end; e += 4) {
        int s0 = csrc[e];     int s1 = csrc[e + 1];
        int s2 = csrc[e + 2]; int s3 = csrc[e + 3];
        uint4 q0 = *(const uint4*)(Yb + (size_t)s0 * 128 + lane * 8);
        uint4 q1 = *(const uint4*)(Yb + (size_t)s1 * 128 + lane * 8);
        uint4 q2 = *(const uint4*)(Yb + (size_t)s2 * 128 + lane * 8);
        uint4 q3 = *(const uint4*)(Yb + (size_t)s3 * 128 + lane * 8);
        bf8_add(q0, acc); bf8_add(q1, acc); bf8_add(q2, acc); bf8_add(q3, acc);
    }
    for (; e < end; ++e) {
        uint4 q = *(const uint4*)(Yb + (size_t)csrc[e] * 128 + lane * 8);
        bf8_add(q, acc);
    }
    float ndv = nd[node];
    float4 b0 = *(const float4*)(bias + lane * 8);
    float4 b1 = *(const float4*)(bias + lane * 8 + 4);
    float o[8];
    o[0] = fmaxf(acc[0] * ndv + b0.x, 0.f); o[1] = fmaxf(acc[1] * ndv + b0.y, 0.f);
    o[2] = fmaxf(acc[2] * ndv + b0.z, 0.f); o[3] = fmaxf(acc[3] * ndv + b0.w, 0.f);
    o[4] = fmaxf(acc[4] * ndv + b1.x, 0.f); o[5] = fmaxf(acc[5] * ndv + b1.y, 0.f);
    o[6] = fmaxf(acc[6] * ndv + b1.z, 0.f); o[7] = fmaxf(acc[7] * ndv + b1.w, 0.f);
    *(float4*)(hout + (size_t)node * 128 + lane * 8)     = make_float4(o[0], o[1], o[2], o[3]);
    *(float4*)(hout + (size_t)node * 128 + lane * 8 + 4) = make_float4(o[4], o[5], o[6], o[7]);
    short8 ob;
    #pragma unroll
    for (int i = 0; i < 8; ++i) ob[i] = (short)f2bf(o[i]);
    *(short8*)&sA[grp][lane * 8] = ob;    // grp*272B + lane*16B: 16-B aligned
    __syncthreads();

    // phase 2: MFMA over the 16x128 LDS tile
    int w = tid >> 6;
    int l = tid & 63;
    int li = l & 15;
    int kg = l >> 4;
    short8 afrag[4];
    #pragma unroll
    for (int kt = 0; kt < 4; ++kt)
        afrag[kt] = *(const short8*)&sA[li][kt * 32 + kg * 8];
    float4 nsv = *(const float4*)(ns + node_base + kg * 4);
    float nsa[4] = {nsv.x, nsv.y, nsv.z, nsv.w};
    #pragma unroll
    for (int n = 0; n < NT; ++n) {
        int col = w * 16 * NT + n * 16 + li;
        short8 bfrag[4];
        #pragma unroll
        for (int kt = 0; kt < 4; ++kt)
            bfrag[kt] = *(const short8*)(WT + (size_t)col * 128 + kt * 32 + kg * 8);
        f32x4 acc2 = {0.f, 0.f, 0.f, 0.f};
        #pragma unroll
        for (int kt = 0; kt < 4; ++kt)
            acc2 = __builtin_amdgcn_mfma_f32_16x16x32_bf16(afrag[kt], bfrag[kt], acc2, 0, 0, 0);
        #pragma unroll
        for (int r = 0; r < 4; ++r)
            Yout[(size_t)(node_base + kg * 4 + r) * NOUT + col] = f2bf(acc2[r] * nsa[r]);
    }
}

// 256 thr = 32 groups x 8 lanes; one node per group; lane owns 8 of 64 feats.
__global__ __launch_bounds__(256)
void k_agg64(const ushort* __restrict__ Yb, const int* __restrict__ rowptr,
             const int* __restrict__ csrc, const float* __restrict__ nd,
             const float* __restrict__ bias, float* __restrict__ out) {
    int tid = threadIdx.x;
    int grp = tid >> 3;
    int lane = tid & 7;
    int node = blockIdx.x * 32 + grp;
    int beg = rowptr[node], end = rowptr[node + 1];
    float acc[8] = {0.f, 0.f, 0.f, 0.f, 0.f, 0.f, 0.f, 0.f};
    int e = beg;
    for (; e + 7 < end; e += 8) {
        int s0 = csrc[e];     int s1 = csrc[e + 1];
        int s2 = csrc[e + 2]; int s3 = csrc[e + 3];
        int s4 = csrc[e + 4]; int s5 = csrc[e + 5];
        int s6 = csrc[e + 6]; int s7 = csrc[e + 7];
        uint4 q0 = *(const uint4*)(Yb + (size_t)s0 * 64 + lane * 8);
        uint4 q1 = *(const uint4*)(Yb + (size_t)s1 * 64 + lane * 8);
        uint4 q2 = *(const uint4*)(Yb + (size_t)s2 * 64 + lane * 8);
        uint4 q3 = *(const uint4*)(Yb + (size_t)s3 * 64 + lane * 8);
        uint4 q4 = *(const uint4*)(Yb + (size_t)s4 * 64 + lane * 8);
        uint4 q5 = *(const uint4*)(Yb + (size_t)s5 * 64 + lane * 8);
        uint4 q6 = *(const uint4*)(Yb + (size_t)s6 * 64 + lane * 8);
        uint4 q7 = *(const uint4*)(Yb + (size_t)s7 * 64 + lane * 8);
        bf8_add(q0, acc); bf8_add(q1, acc); bf8_add(q2, acc); bf8_add(q3, acc);
        bf8_add(q4, acc); bf8_add(q5, acc); bf8_add(q6, acc); bf8_add(q7, acc);
    }
    for (; e + 3 < end; e += 4) {
        int s0 = csrc[e];     int s1 = csrc[e + 1];
        int s2 = csrc[e + 2]; int s3 = csrc[e + 3];
        uint4 q0 = *(const uint4*)(Yb + (size_t)s0 * 64 + lane * 8);
        uint4 q1 = *(const uint4*)(Yb + (size_t)s1 * 64 + lane * 8);
        uint4 q2 = *(const uint4*)(Yb + (size_t)s2 * 64 + lane * 8);
        uint4 q3 = *(const uint4*)(Yb + (size_t)s3 * 64 + lane * 8);
        bf8_add(q0, acc); bf8_add(q1, acc); bf8_add(q2, acc); bf8_add(q3, acc);
    }
    for (; e < end; ++e) {
        uint4 q = *(const uint4*)(Yb + (size_t)csrc[e] * 64 + lane * 8);
        bf8_add(q, acc);
    }
    float ndv = nd[node];
    float4 b0 = *(const float4*)(bias + lane * 8);
    float4 b1 = *(const float4*)(bias + lane * 8 + 4);
    float4 o0, o1;
    o0.x = acc[0] * ndv + b0.x; o0.y = acc[1] * ndv + b0.y;
    o0.z = acc[2] * ndv + b0.z; o0.w = acc[3] * ndv + b0.w;
    o1.x = acc[4] * ndv + b1.x; o1.y = acc[5] * ndv + b1.y;
    o1.z = acc[6] * ndv + b1.z; o1.w = acc[7] * ndv + b1.w;
    *(float4*)(out + (size_t)node * 64 + lane * 8)     = o0;
    *(float4*)(out + (size_t)node * 64 + lane * 8 + 4) = o1;
}

// ---------------- launch ----------------

extern "C" void kernel_launch(void* const* d_in, const int* in_sizes, int n_in,
                              void* d_out, int out_size, void* d_ws, size_t ws_size,
                              hipStream_t stream) {
    const float* x  = (const float*)d_in[0];
    const int* esrc = (const int*)d_in[1];
    const int* edst = (const int*)d_in[2];
    const float* W0 = (const float*)d_in[3];
    const float* b0 = (const float*)d_in[4];
    const float* W1 = (const float*)d_in[5];
    const float* b1 = (const float*)d_in[6];
    const float* W2 = (const float*)d_in[7];
    const float* b2 = (const float*)d_in[8];
    float* out = (float*)d_out;

    // workspace (~40 MB). No trailing backslashes in comments.
    float* ns      = (float*)d_ws;                // NN
    float* nd      = ns + NN;                     // NN
    int*   csum    = (int*)(nd + NN);             // NN
    int*   rowptr  = csum + NN;                   // NN+8
    int*   bsum    = rowptr + NN + 8;             // 512
    int*   bsumex  = bsum + 512;                  // 512
    int*   csrc    = bsumex + 512;                // NE
    uchar* pout    = (uchar*)(csrc + NE);         // KR*RSL*RS = 8 MB
    uchar* pin     = pout + (size_t)KR * RSL * RS;// 8 MB
    ushort* WT0    = (ushort*)(pin + (size_t)KR * RSL * RS);  // 128*128
    ushort* WT1    = WT0 + 128 * 128;             // 128*128
    ushort* WT2    = WT1 + 128 * 128;             // 64*128
    ushort* Y2b    = WT2 + 64 * 128;              // NN*64 bf16

    // output chunks
    float* h1 = out + (size_t)NN * 128;
    float* h2 = h1 + (size_t)NN * 128;
    float* h3 = h2 + (size_t)NN * 128;            // NN*64 floats

    // bf16 GEMM outputs parked in dead output slots:
    //  Y0b in h2 slot (last read: aggGemm layer1; h2 written layer2)
    //  Y1b in h3 slot (last read: aggGemm layer2; h3 written agg64)
    ushort* Y0b = (ushort*)h2;                    // NN*128 bf16
    ushort* Y1b = (ushort*)h3;                    // NN*128 bf16

    // 1. degree histograms (LDS-privatized, no global atomics)
    k_hist<<<KR * RSL, 256, 0, stream>>>(esrc, edst, pout, pin);

    // 2. reduce -> ns/nd/csum (+fused block sums); pin becomes r-prefix
    k_red<<<NB, 256, 0, stream>>>(pout, pin, ns, nd, csum, bsum);

    // 3. scan -> rowptr
    k_scanb<<<1, 512, 0, stream>>>(bsum, bsumex, rowptr);
    k_rowptr<<<NB, 256, 0, stream>>>(csum, bsumex, rowptr);

    // 4. fill CSR via LDS cursors (no global atomics)
    k_fill<<<KR * RSL, 256, 0, stream>>>(esrc, edst, pin, rowptr, csrc);

    // 5. weight transposes (one kernel)
    k_wtall<<<160, 256, 0, stream>>>(W0, W1, W2, WT0);

    // 6. layer-1 GEMM (reads fp32 x, fused out0 passthrough)
    k_gemm1<<<1024, 256, 0, stream>>>(x, WT0, ns, Y0b, out);

    // 7. fused agg(layer1)+GEMM(layer2): h1 + Y1b
    k_agg_gemm<128><<<NN / 16, 256, 0, stream>>>(Y0b, rowptr, csrc, nd, b0, ns,
                                                 WT1, h1, Y1b);

    // 8. fused agg(layer2)+GEMM(layer3): h2 + Y2b
    k_agg_gemm<64><<<NN / 16, 256, 0, stream>>>(Y1b, rowptr, csrc, nd, b1, ns,
                                                WT2, h2, Y2b);

    // 9. final aggregation -> h3
    k_agg64<<<NN / 32, 256, 0, stream>>>(Y2b, rowptr, csrc, nd, b2, h3);
}